// Round 1
// baseline (1748.995 us; speedup 1.0000x reference)
//
#include <hip/hip_runtime.h>
#include <math.h>

#define Dm    256
#define NHm   8
#define DHm   32
#define NLEVm 4
#define NPTSm 4
#define DFFNm 1024
#define Bm    8
#define LQm   900
#define LENm  13294
#define MQ    (Bm * LQm)      // 7200
#define MV    (Bm * LENm)     // 106352

// -------------------- elementwise add (float4) --------------------
__global__ __launch_bounds__(256) void add_kernel(const float* __restrict__ a,
                                                  const float* __restrict__ b,
                                                  float* __restrict__ o, int n4) {
    int i = blockIdx.x * blockDim.x + threadIdx.x;
    int stride = gridDim.x * blockDim.x;
    for (; i < n4; i += stride) {
        float4 x = reinterpret_cast<const float4*>(a)[i];
        float4 y = reinterpret_cast<const float4*>(b)[i];
        reinterpret_cast<float4*>(o)[i] = make_float4(x.x + y.x, x.y + y.y, x.z + y.z, x.w + y.w);
    }
}

// -------------------- tiled SGEMM: C = A(MxK) @ W(KxN) + bias, opt ReLU ---
// 64x64 tile, BK=16, 256 threads, 4x4 microtile. N,K multiples of 64/16; M guarded.
template <int RELU>
__global__ __launch_bounds__(256) void sgemm(int M, int N, int K,
                                             const float* __restrict__ A, int lda,
                                             const float* __restrict__ W, int ldw,
                                             const float* __restrict__ bias,
                                             float* __restrict__ C, int ldc) {
    __shared__ float As[16][64];  // [k][row]
    __shared__ float Ws[16][64];  // [k][col]
    int row0 = blockIdx.x * 64;
    int col0 = blockIdx.y * 64;
    int tid = threadIdx.x;
    int tx = tid & 15, ty = tid >> 4;
    float acc[4][4] = {};
    for (int k0 = 0; k0 < K; k0 += 16) {
        // A tile 64x16, each thread loads 4 consecutive k-elems of one row
        {
            int e = tid * 4;
            int r = e >> 4;      // row in tile
            int c = e & 15;      // k in tile
            int grow = row0 + r;
            float4 v = make_float4(0.f, 0.f, 0.f, 0.f);
            if (grow < M)
                v = *reinterpret_cast<const float4*>(&A[(size_t)grow * lda + k0 + c]);
            As[c + 0][r] = v.x; As[c + 1][r] = v.y; As[c + 2][r] = v.z; As[c + 3][r] = v.w;
        }
        // W tile 16x64
        {
            int e = tid * 4;
            int r = e >> 6;      // k in tile
            int c = e & 63;      // col in tile
            float4 v = *reinterpret_cast<const float4*>(&W[(size_t)(k0 + r) * ldw + col0 + c]);
            Ws[r][c + 0] = v.x; Ws[r][c + 1] = v.y; Ws[r][c + 2] = v.z; Ws[r][c + 3] = v.w;
        }
        __syncthreads();
        #pragma unroll
        for (int kk = 0; kk < 16; kk++) {
            float a[4], w[4];
            #pragma unroll
            for (int i = 0; i < 4; i++) a[i] = As[kk][ty * 4 + i];
            #pragma unroll
            for (int j = 0; j < 4; j++) w[j] = Ws[kk][tx * 4 + j];
            #pragma unroll
            for (int i = 0; i < 4; i++)
                #pragma unroll
                for (int j = 0; j < 4; j++) acc[i][j] += a[i] * w[j];
        }
        __syncthreads();
    }
    #pragma unroll
    for (int i = 0; i < 4; i++) {
        int r = row0 + ty * 4 + i;
        if (r >= M) continue;
        #pragma unroll
        for (int j = 0; j < 4; j++) {
            int c = col0 + tx * 4 + j;
            float v = acc[i][j] + bias[c];
            if (RELU) v = fmaxf(v, 0.f);
            C[(size_t)r * ldc + c] = v;
        }
    }
}

// -------------------- self-attention: one block per (b,h,q) --------------------
__global__ __launch_bounds__(256) void attn_kernel(const float* __restrict__ qk,  // (MQ,512): [qh|kh]
                                                   const float* __restrict__ vh,  // (MQ,256)
                                                   float* __restrict__ out) {     // (MQ,256)
    int blk = blockIdx.x;
    int qi = blk % LQm;
    int h = (blk / LQm) % NHm;
    int b = blk / (LQm * NHm);
    int tid = threadIdx.x;
    __shared__ float qrow[DHm];
    __shared__ float sbuf[LQm];
    __shared__ float red[256];
    int m = b * LQm + qi;
    if (tid < DHm) qrow[tid] = qk[(size_t)m * 512 + h * DHm + tid];
    __syncthreads();
    const float scale = 0.17677669529663687f;  // 1/sqrt(32)
    float lmax = -1e30f;
    #pragma unroll
    for (int ii = 0; ii < 4; ii++) {
        int k = tid + ii * 256;
        if (k < LQm) {
            const float* kr = &qk[(size_t)(b * LQm + k) * 512 + 256 + h * DHm];
            float s = 0.f;
            #pragma unroll
            for (int d = 0; d < DHm; d++) s += qrow[d] * kr[d];
            s *= scale;
            sbuf[k] = s;
            lmax = fmaxf(lmax, s);
        }
    }
    red[tid] = lmax;
    __syncthreads();
    for (int s2 = 128; s2 > 0; s2 >>= 1) {
        if (tid < s2) red[tid] = fmaxf(red[tid], red[tid + s2]);
        __syncthreads();
    }
    float gmax = red[0];
    __syncthreads();
    float lsum = 0.f;
    #pragma unroll
    for (int ii = 0; ii < 4; ii++) {
        int k = tid + ii * 256;
        if (k < LQm) {
            float p = __expf(sbuf[k] - gmax);
            sbuf[k] = p;
            lsum += p;
        }
    }
    red[tid] = lsum;
    __syncthreads();
    for (int s2 = 128; s2 > 0; s2 >>= 1) {
        if (tid < s2) red[tid] += red[tid + s2];
        __syncthreads();
    }
    float inv = 1.0f / red[0];
    __syncthreads();
    // PV: tid -> (group g over keys, dim d)
    int d = tid & 31, g = tid >> 5;
    float acc = 0.f;
    for (int k = g; k < LQm; k += 8)
        acc += sbuf[k] * vh[(size_t)(b * LQm + k) * 256 + h * DHm + d];
    red[tid] = acc;
    __syncthreads();
    if (g == 0) {
        float t = 0.f;
        #pragma unroll
        for (int gg = 0; gg < 8; gg++) t += red[gg * 32 + d];
        out[(size_t)m * 256 + h * DHm + d] = t * inv;
    }
}

// -------------------- fused residual add + LayerNorm (one row / block) ------
__global__ __launch_bounds__(256) void add_ln_kernel(const float* __restrict__ x,
                                                     const float* __restrict__ r,
                                                     const float* __restrict__ w,
                                                     const float* __restrict__ b,
                                                     float* __restrict__ out) {
    int row = blockIdx.x;
    int t = threadIdx.x;
    __shared__ float red[256];
    float v = x[(size_t)row * Dm + t] + r[(size_t)row * Dm + t];
    red[t] = v;
    __syncthreads();
    for (int s = 128; s > 0; s >>= 1) {
        if (t < s) red[t] += red[t + s];
        __syncthreads();
    }
    float mean = red[0] * (1.0f / Dm);
    __syncthreads();
    float dv = v - mean;
    red[t] = dv * dv;
    __syncthreads();
    for (int s = 128; s > 0; s >>= 1) {
        if (t < s) red[t] += red[t + s];
        __syncthreads();
    }
    float var = red[0] * (1.0f / Dm);
    out[(size_t)row * Dm + t] = dv * rsqrtf(var + 1e-5f) * w[t] + b[t];
}

// -------------------- ms-deformable attention sampling --------------------
__global__ __launch_bounds__(256) void msdeform_kernel(const float* __restrict__ value, // (MV,256)
                                                       const float* __restrict__ ref,   // (B,LQ,4,2)
                                                       const float* __restrict__ off,   // (MQ,256)
                                                       const float* __restrict__ awl,   // (MQ,128)
                                                       float* __restrict__ out) {       // (MQ,256)
    const int HL[4] = {100, 50, 25, 13};
    const int WL[4] = {100, 50, 25, 13};
    const int ST[4] = {0, 10000, 12500, 13125};
    int m = blockIdx.x;           // b*LQ + lq
    int b = m / LQm;
    int t = threadIdx.x;
    __shared__ float lsx[NHm][16], lsy[NHm][16], wgt[NHm][16];
    if (t < 128) {
        int h = t >> 4, i = t & 15;
        int lev = i >> 2, pt = i & 3;
        float rx = ref[((size_t)m * NLEVm + lev) * 2 + 0];
        float ry = ref[((size_t)m * NLEVm + lev) * 2 + 1];
        float ox = off[(size_t)m * 256 + (size_t)((h * NLEVm + lev) * NPTSm + pt) * 2 + 0];
        float oy = off[(size_t)m * 256 + (size_t)((h * NLEVm + lev) * NPTSm + pt) * 2 + 1];
        float Wf = (float)WL[lev], Hf = (float)HL[lev];
        lsx[h][i] = (rx + ox / Wf) * Wf - 0.5f;
        lsy[h][i] = (ry + oy / Hf) * Hf - 0.5f;
        wgt[h][i] = awl[(size_t)m * 128 + h * 16 + i];
    }
    __syncthreads();
    if (t < NHm) {
        int h = t;
        float mx = -1e30f;
        #pragma unroll
        for (int i = 0; i < 16; i++) mx = fmaxf(mx, wgt[h][i]);
        float s = 0.f;
        #pragma unroll
        for (int i = 0; i < 16; i++) { float e = __expf(wgt[h][i] - mx); wgt[h][i] = e; s += e; }
        float inv = 1.0f / s;
        #pragma unroll
        for (int i = 0; i < 16; i++) wgt[h][i] *= inv;
    }
    __syncthreads();
    int h = t >> 5, d = t & 31;
    float acc = 0.f;
    #pragma unroll
    for (int i = 0; i < 16; i++) {
        int lev = i >> 2;
        float lx = lsx[h][i], ly = lsy[h][i];
        int Wl = WL[lev], Hl = HL[lev];
        float x0f = floorf(lx), y0f = floorf(ly);
        float fx = lx - x0f, fy = ly - y0f;
        int x0 = (int)x0f, y0 = (int)y0f;
        float aw = wgt[h][i];
        const float* vbase = value + ((size_t)(b * LENm + ST[lev])) * 256 + h * DHm + d;
        #pragma unroll
        for (int c = 0; c < 4; c++) {
            int dx = c & 1, dy = c >> 1;
            int xi = x0 + dx, yi = y0 + dy;
            if (xi >= 0 && xi < Wl && yi >= 0 && yi < Hl) {
                float w = (dx ? fx : 1.0f - fx) * (dy ? fy : 1.0f - fy);
                acc += aw * w * vbase[(size_t)(yi * Wl + xi) * 256];
            }
        }
    }
    out[(size_t)m * 256 + h * DHm + d] = acc;
}

// ------------------------------------------------------------------
extern "C" void kernel_launch(void* const* d_in, const int* in_sizes, int n_in,
                              void* d_out, int out_size, void* d_ws, size_t ws_size,
                              hipStream_t stream) {
    const float* tgt   = (const float*)d_in[0];
    const float* qpos  = (const float*)d_in[1];
    const float* refp  = (const float*)d_in[2];
    const float* src   = (const float*)d_in[3];
    const float* qkv_w = (const float*)d_in[6];
    const float* qkv_b = (const float*)d_in[7];
    const float* out_w = (const float*)d_in[8];
    const float* out_b = (const float*)d_in[9];
    const float* ln2_w = (const float*)d_in[10];
    const float* ln2_b = (const float*)d_in[11];
    const float* val_w = (const float*)d_in[12];
    const float* val_b = (const float*)d_in[13];
    const float* off_w = (const float*)d_in[14];
    const float* off_b = (const float*)d_in[15];
    const float* aw_w  = (const float*)d_in[16];
    const float* aw_b  = (const float*)d_in[17];
    const float* op_w  = (const float*)d_in[18];
    const float* op_b  = (const float*)d_in[19];
    const float* ln1_w = (const float*)d_in[20];
    const float* ln1_b = (const float*)d_in[21];
    const float* w1    = (const float*)d_in[22];
    const float* b1    = (const float*)d_in[23];
    const float* w2    = (const float*)d_in[24];
    const float* b2    = (const float*)d_in[25];
    const float* ln3_w = (const float*)d_in[26];
    const float* ln3_b = (const float*)d_in[27];

    float* ws    = (float*)d_ws;
    float* value = ws;                       // 106352*256 = 27,226,112
    float* buf1  = value + 27226112;         // 7200*1024  =  7,372,800 (qh|kh, later ffn hidden)
    float* vhb   = buf1 + 7372800;           // 7200*256 each below
    float* buf3  = vhb + 1843200;
    float* buf4  = buf3 + 1843200;
    float* buf5  = buf4 + 1843200;
    float* t1b   = buf5 + 1843200;
    float* awb   = t1b + 1843200;            // 7200*128 = 921,600
    float* outp  = (float*)d_out;

    dim3 blk(256);
    // 1. q = tgt + query_pos -> buf4
    add_kernel<<<dim3(1800), blk, 0, stream>>>(tgt, qpos, buf4, MQ * Dm / 4);
    // 2. [qh|kh] = q @ qkv_w[:, :512] + qkv_b[:512] -> buf1 (ldc 512)
    sgemm<0><<<dim3((MQ + 63) / 64, 512 / 64), blk, 0, stream>>>(MQ, 512, Dm, buf4, Dm, qkv_w, 768, qkv_b, buf1, 512);
    // 3. vh = tgt @ qkv_w[:, 512:] + qkv_b[512:] -> vhb
    sgemm<0><<<dim3((MQ + 63) / 64, 256 / 64), blk, 0, stream>>>(MQ, 256, Dm, tgt, Dm, qkv_w + 512, 768, qkv_b + 512, vhb, 256);
    // 4. self-attention -> buf3
    attn_kernel<<<dim3(Bm * NHm * LQm), blk, 0, stream>>>(buf1, vhb, buf3);
    // 5. sa proj -> buf5
    sgemm<0><<<dim3((MQ + 63) / 64, 256 / 64), blk, 0, stream>>>(MQ, 256, Dm, buf3, Dm, out_w, 256, out_b, buf5, 256);
    // 6. t1 = LN(tgt + sa; ln2) -> t1b
    add_ln_kernel<<<dim3(MQ), blk, 0, stream>>>(tgt, buf5, ln2_w, ln2_b, t1b);
    // 7. q2 = t1 + query_pos -> buf4
    add_kernel<<<dim3(1800), blk, 0, stream>>>(t1b, qpos, buf4, MQ * Dm / 4);
    // 8. value = src @ val_w + val_b -> value
    sgemm<0><<<dim3((MV + 63) / 64, 256 / 64), blk, 0, stream>>>(MV, 256, Dm, src, Dm, val_w, 256, val_b, value, 256);
    // 9. off = q2 @ off_w + off_b -> buf3
    sgemm<0><<<dim3((MQ + 63) / 64, 256 / 64), blk, 0, stream>>>(MQ, 256, Dm, buf4, Dm, off_w, 256, off_b, buf3, 256);
    // 10. aw logits = q2 @ aw_w + aw_b -> awb
    sgemm<0><<<dim3((MQ + 63) / 64, 128 / 64), blk, 0, stream>>>(MQ, 128, Dm, buf4, Dm, aw_w, 128, aw_b, awb, 128);
    // 11. msdeform sampling -> vhb (reuse)
    msdeform_kernel<<<dim3(MQ), blk, 0, stream>>>(value, refp, buf3, awb, vhb);
    // 12. op proj -> buf5
    sgemm<0><<<dim3((MQ + 63) / 64, 256 / 64), blk, 0, stream>>>(MQ, 256, Dm, vhb, Dm, op_w, 256, op_b, buf5, 256);
    // 13. t2 = LN(t1 + ca; ln1) -> buf4
    add_ln_kernel<<<dim3(MQ), blk, 0, stream>>>(t1b, buf5, ln1_w, ln1_b, buf4);
    // 14. ffn hidden = relu(t2 @ w1 + b1) -> buf1
    sgemm<1><<<dim3((MQ + 63) / 64, DFFNm / 64), blk, 0, stream>>>(MQ, DFFNm, Dm, buf4, Dm, w1, DFFNm, b1, buf1, DFFNm);
    // 15. ff = hidden @ w2 + b2 -> buf5
    sgemm<0><<<dim3((MQ + 63) / 64, 256 / 64), blk, 0, stream>>>(MQ, 256, DFFNm, buf1, DFFNm, w2, 256, b2, buf5, 256);
    // 16. out = LN(t2 + ff; ln3) -> d_out
    add_ln_kernel<<<dim3(MQ), blk, 0, stream>>>(buf4, buf5, ln3_w, ln3_b, outp);
}

// Round 2
// 779.286 us; speedup vs baseline: 2.2444x; 2.2444x over previous
//
#include <hip/hip_runtime.h>
#include <math.h>

#define Dm    256
#define NHm   8
#define DHm   32
#define NLEVm 4
#define NPTSm 4
#define DFFNm 1024
#define Bm    8
#define LQm   900
#define LENm  13294
#define MQ    (Bm * LQm)      // 7200
#define MV    (Bm * LENm)     // 106352

// -------------------- elementwise add (float4) --------------------
__global__ __launch_bounds__(256) void add_kernel(const float* __restrict__ a,
                                                  const float* __restrict__ b,
                                                  float* __restrict__ o, int n4) {
    int i = blockIdx.x * blockDim.x + threadIdx.x;
    int stride = gridDim.x * blockDim.x;
    for (; i < n4; i += stride) {
        float4 x = reinterpret_cast<const float4*>(a)[i];
        float4 y = reinterpret_cast<const float4*>(b)[i];
        reinterpret_cast<float4*>(o)[i] = make_float4(x.x + y.x, x.y + y.y, x.z + y.z, x.w + y.w);
    }
}

// -------------------- tiled SGEMM: C = A(MxK) @ W(KxN) + bias, opt ReLU ---
template <int RELU>
__global__ __launch_bounds__(256) void sgemm(int M, int N, int K,
                                             const float* __restrict__ A, int lda,
                                             const float* __restrict__ W, int ldw,
                                             const float* __restrict__ bias,
                                             float* __restrict__ C, int ldc) {
    __shared__ float As[16][64];  // [k][row]
    __shared__ float Ws[16][64];  // [k][col]
    int row0 = blockIdx.x * 64;
    int col0 = blockIdx.y * 64;
    int tid = threadIdx.x;
    int tx = tid & 15, ty = tid >> 4;
    float acc[4][4] = {};
    for (int k0 = 0; k0 < K; k0 += 16) {
        {
            int e = tid * 4;
            int r = e >> 4;
            int c = e & 15;
            int grow = row0 + r;
            float4 v = make_float4(0.f, 0.f, 0.f, 0.f);
            if (grow < M)
                v = *reinterpret_cast<const float4*>(&A[(size_t)grow * lda + k0 + c]);
            As[c + 0][r] = v.x; As[c + 1][r] = v.y; As[c + 2][r] = v.z; As[c + 3][r] = v.w;
        }
        {
            int e = tid * 4;
            int r = e >> 6;
            int c = e & 63;
            float4 v = *reinterpret_cast<const float4*>(&W[(size_t)(k0 + r) * ldw + col0 + c]);
            Ws[r][c + 0] = v.x; Ws[r][c + 1] = v.y; Ws[r][c + 2] = v.z; Ws[r][c + 3] = v.w;
        }
        __syncthreads();
        #pragma unroll
        for (int kk = 0; kk < 16; kk++) {
            float a[4], w[4];
            #pragma unroll
            for (int i = 0; i < 4; i++) a[i] = As[kk][ty * 4 + i];
            #pragma unroll
            for (int j = 0; j < 4; j++) w[j] = Ws[kk][tx * 4 + j];
            #pragma unroll
            for (int i = 0; i < 4; i++)
                #pragma unroll
                for (int j = 0; j < 4; j++) acc[i][j] += a[i] * w[j];
        }
        __syncthreads();
    }
    #pragma unroll
    for (int i = 0; i < 4; i++) {
        int r = row0 + ty * 4 + i;
        if (r >= M) continue;
        #pragma unroll
        for (int j = 0; j < 4; j++) {
            int c = col0 + tx * 4 + j;
            float v = acc[i][j] + bias[c];
            if (RELU) v = fmaxf(v, 0.f);
            C[(size_t)r * ldc + c] = v;
        }
    }
}

// -------------------- flash self-attention --------------------
// grid (15, NH, B); block 256. Q-tile 64, K-tile 64, online softmax.
__global__ __launch_bounds__(256) void flash_attn(const float* __restrict__ qk,  // (MQ,512): [qh|kh]
                                                  const float* __restrict__ vh,  // (MQ,256)
                                                  float* __restrict__ out) {     // (MQ,256)
    __shared__ float Qs[64][36];
    __shared__ float Ks[64][36];
    __shared__ float Vs[64][36];
    __shared__ float Ps[64][68];
    __shared__ float ms[64], ls[64], rs[64];

    int t = threadIdx.x;
    int q0 = blockIdx.x * 64;
    int h = blockIdx.y;
    int b = blockIdx.z;
    const float scale = 0.17677669529663687f;  // 1/sqrt(32)

    // load Q tile (64 rows x 32 dims), zero-fill OOB rows
    {
        const float* Qbase = qk + (size_t)(b * LQm + q0) * 512 + h * DHm;
        #pragma unroll
        for (int e = t; e < 512; e += 256) {
            int r = e >> 3, c = e & 7;
            float4 v = make_float4(0.f, 0.f, 0.f, 0.f);
            if (q0 + r < LQm) v = *reinterpret_cast<const float4*>(Qbase + (size_t)r * 512 + c * 4);
            *reinterpret_cast<float4*>(&Qs[r][c * 4]) = v;
        }
    }
    if (t < 64) { ms[t] = -1e30f; ls[t] = 0.f; }

    // scores identity
    int qg = t >> 4;       // 0..15 -> queries qg*4 + i
    int kg = t & 15;       // keys kg + 16*j
    // PV identity
    int q_pv = t >> 2;     // 0..63
    int dg = t & 3;        // dims dg*8 .. dg*8+7
    float acc[8] = {0.f, 0.f, 0.f, 0.f, 0.f, 0.f, 0.f, 0.f};

    for (int k0 = 0; k0 < LQm; k0 += 64) {
        __syncthreads();   // protect Ks/Vs/Ps from previous iteration readers
        // load K, V tiles
        {
            const float* Kbase = qk + (size_t)(b * LQm + k0) * 512 + 256 + h * DHm;
            const float* Vbase = vh + (size_t)(b * LQm + k0) * 256 + h * DHm;
            #pragma unroll
            for (int e = t; e < 512; e += 256) {
                int r = e >> 3, c = e & 7;
                float4 kv4 = make_float4(0.f, 0.f, 0.f, 0.f);
                float4 vv4 = make_float4(0.f, 0.f, 0.f, 0.f);
                if (k0 + r < LQm) {
                    kv4 = *reinterpret_cast<const float4*>(Kbase + (size_t)r * 512 + c * 4);
                    vv4 = *reinterpret_cast<const float4*>(Vbase + (size_t)r * 256 + c * 4);
                }
                *reinterpret_cast<float4*>(&Ks[r][c * 4]) = kv4;
                *reinterpret_cast<float4*>(&Vs[r][c * 4]) = vv4;
            }
        }
        __syncthreads();

        // ---- scores: 4q x 4k microtile ----
        float s[4][4] = {};
        for (int d4 = 0; d4 < 8; d4++) {
            float4 qv[4], kv[4];
            #pragma unroll
            for (int i = 0; i < 4; i++) qv[i] = *reinterpret_cast<const float4*>(&Qs[qg * 4 + i][d4 * 4]);
            #pragma unroll
            for (int j = 0; j < 4; j++) kv[j] = *reinterpret_cast<const float4*>(&Ks[kg + 16 * j][d4 * 4]);
            #pragma unroll
            for (int i = 0; i < 4; i++)
                #pragma unroll
                for (int j = 0; j < 4; j++) {
                    s[i][j] += qv[i].x * kv[j].x + qv[i].y * kv[j].y +
                               qv[i].z * kv[j].z + qv[i].w * kv[j].w;
                }
        }
        #pragma unroll
        for (int i = 0; i < 4; i++)
            #pragma unroll
            for (int j = 0; j < 4; j++) {
                s[i][j] *= scale;
                if (k0 + kg + 16 * j >= LQm) s[i][j] = -1e30f;
            }

        // tile row-max over 64 keys: local 4 then 16-lane allreduce
        float tm[4], mold[4], newm[4];
        #pragma unroll
        for (int i = 0; i < 4; i++) {
            tm[i] = fmaxf(fmaxf(s[i][0], s[i][1]), fmaxf(s[i][2], s[i][3]));
        }
        #pragma unroll
        for (int msk = 1; msk <= 8; msk <<= 1) {
            #pragma unroll
            for (int i = 0; i < 4; i++) tm[i] = fmaxf(tm[i], __shfl_xor(tm[i], msk));
        }
        #pragma unroll
        for (int i = 0; i < 4; i++) {
            mold[i] = ms[qg * 4 + i];
            newm[i] = fmaxf(mold[i], tm[i]);
        }
        float p[4][4], psum[4];
        #pragma unroll
        for (int i = 0; i < 4; i++) {
            psum[i] = 0.f;
            #pragma unroll
            for (int j = 0; j < 4; j++) {
                p[i][j] = __expf(s[i][j] - newm[i]);
                psum[i] += p[i][j];
            }
        }
        #pragma unroll
        for (int msk = 1; msk <= 8; msk <<= 1) {
            #pragma unroll
            for (int i = 0; i < 4; i++) psum[i] += __shfl_xor(psum[i], msk);
        }
        if (kg == 0) {
            #pragma unroll
            for (int i = 0; i < 4; i++) {
                int q = qg * 4 + i;
                float r_ = __expf(mold[i] - newm[i]);
                rs[q] = r_;
                ls[q] = ls[q] * r_ + psum[i];
                ms[q] = newm[i];
            }
        }
        // write P tile
        #pragma unroll
        for (int i = 0; i < 4; i++)
            #pragma unroll
            for (int j = 0; j < 4; j++)
                Ps[qg * 4 + i][kg + 16 * j] = p[i][j];
        __syncthreads();

        // ---- PV: 1q x 8d per thread ----
        float rsc = rs[q_pv];
        #pragma unroll
        for (int n = 0; n < 8; n++) acc[n] *= rsc;
        for (int kk4 = 0; kk4 < 16; kk4++) {
            float4 p4 = *reinterpret_cast<const float4*>(&Ps[q_pv][kk4 * 4]);
            #pragma unroll
            for (int u = 0; u < 4; u++) {
                float pv = (&p4.x)[u];
                float4 v0 = *reinterpret_cast<const float4*>(&Vs[kk4 * 4 + u][dg * 8]);
                float4 v1 = *reinterpret_cast<const float4*>(&Vs[kk4 * 4 + u][dg * 8 + 4]);
                acc[0] += pv * v0.x; acc[1] += pv * v0.y; acc[2] += pv * v0.z; acc[3] += pv * v0.w;
                acc[4] += pv * v1.x; acc[5] += pv * v1.y; acc[6] += pv * v1.z; acc[7] += pv * v1.w;
            }
        }
    }
    __syncthreads();
    if (q0 + q_pv < LQm) {
        float inv = 1.0f / ls[q_pv];
        float* ob = out + (size_t)(b * LQm + q0 + q_pv) * 256 + h * DHm + dg * 8;
        float4 o0 = make_float4(acc[0] * inv, acc[1] * inv, acc[2] * inv, acc[3] * inv);
        float4 o1 = make_float4(acc[4] * inv, acc[5] * inv, acc[6] * inv, acc[7] * inv);
        *reinterpret_cast<float4*>(ob) = o0;
        *reinterpret_cast<float4*>(ob + 4) = o1;
    }
}

// -------------------- fused residual add + LayerNorm (one row / block) ------
__global__ __launch_bounds__(256) void add_ln_kernel(const float* __restrict__ x,
                                                     const float* __restrict__ r,
                                                     const float* __restrict__ w,
                                                     const float* __restrict__ b,
                                                     float* __restrict__ out) {
    int row = blockIdx.x;
    int t = threadIdx.x;
    __shared__ float red[256];
    float v = x[(size_t)row * Dm + t] + r[(size_t)row * Dm + t];
    red[t] = v;
    __syncthreads();
    for (int s = 128; s > 0; s >>= 1) {
        if (t < s) red[t] += red[t + s];
        __syncthreads();
    }
    float mean = red[0] * (1.0f / Dm);
    __syncthreads();
    float dv = v - mean;
    red[t] = dv * dv;
    __syncthreads();
    for (int s = 128; s > 0; s >>= 1) {
        if (t < s) red[t] += red[t + s];
        __syncthreads();
    }
    float var = red[0] * (1.0f / Dm);
    out[(size_t)row * Dm + t] = dv * rsqrtf(var + 1e-5f) * w[t] + b[t];
}

// -------------------- ms-deformable attention sampling --------------------
__global__ __launch_bounds__(256) void msdeform_kernel(const float* __restrict__ value, // (MV,256)
                                                       const float* __restrict__ ref,   // (B,LQ,4,2)
                                                       const float* __restrict__ off,   // (MQ,256)
                                                       const float* __restrict__ awl,   // (MQ,128)
                                                       float* __restrict__ out) {       // (MQ,256)
    const int HL[4] = {100, 50, 25, 13};
    const int WL[4] = {100, 50, 25, 13};
    const int ST[4] = {0, 10000, 12500, 13125};
    int m = blockIdx.x;
    int b = m / LQm;
    int t = threadIdx.x;
    __shared__ float lsx[NHm][16], lsy[NHm][16], wgt[NHm][16];
    if (t < 128) {
        int h = t >> 4, i = t & 15;
        int lev = i >> 2, pt = i & 3;
        float rx = ref[((size_t)m * NLEVm + lev) * 2 + 0];
        float ry = ref[((size_t)m * NLEVm + lev) * 2 + 1];
        float ox = off[(size_t)m * 256 + (size_t)((h * NLEVm + lev) * NPTSm + pt) * 2 + 0];
        float oy = off[(size_t)m * 256 + (size_t)((h * NLEVm + lev) * NPTSm + pt) * 2 + 1];
        float Wf = (float)WL[lev], Hf = (float)HL[lev];
        lsx[h][i] = (rx + ox / Wf) * Wf - 0.5f;
        lsy[h][i] = (ry + oy / Hf) * Hf - 0.5f;
        wgt[h][i] = awl[(size_t)m * 128 + h * 16 + i];
    }
    __syncthreads();
    if (t < NHm) {
        int h = t;
        float mx = -1e30f;
        #pragma unroll
        for (int i = 0; i < 16; i++) mx = fmaxf(mx, wgt[h][i]);
        float s = 0.f;
        #pragma unroll
        for (int i = 0; i < 16; i++) { float e = __expf(wgt[h][i] - mx); wgt[h][i] = e; s += e; }
        float inv = 1.0f / s;
        #pragma unroll
        for (int i = 0; i < 16; i++) wgt[h][i] *= inv;
    }
    __syncthreads();
    int h = t >> 5, d = t & 31;
    float acc = 0.f;
    #pragma unroll
    for (int i = 0; i < 16; i++) {
        int lev = i >> 2;
        float lx = lsx[h][i], ly = lsy[h][i];
        int Wl = WL[lev], Hl = HL[lev];
        float x0f = floorf(lx), y0f = floorf(ly);
        float fx = lx - x0f, fy = ly - y0f;
        int x0 = (int)x0f, y0 = (int)y0f;
        float aw = wgt[h][i];
        const float* vbase = value + ((size_t)(b * LENm + ST[lev])) * 256 + h * DHm + d;
        #pragma unroll
        for (int c = 0; c < 4; c++) {
            int dx = c & 1, dy = c >> 1;
            int xi = x0 + dx, yi = y0 + dy;
            if (xi >= 0 && xi < Wl && yi >= 0 && yi < Hl) {
                float w = (dx ? fx : 1.0f - fx) * (dy ? fy : 1.0f - fy);
                acc += aw * w * vbase[(size_t)(yi * Wl + xi) * 256];
            }
        }
    }
    out[(size_t)m * 256 + h * DHm + d] = acc;
}

// ------------------------------------------------------------------
extern "C" void kernel_launch(void* const* d_in, const int* in_sizes, int n_in,
                              void* d_out, int out_size, void* d_ws, size_t ws_size,
                              hipStream_t stream) {
    const float* tgt   = (const float*)d_in[0];
    const float* qpos  = (const float*)d_in[1];
    const float* refp  = (const float*)d_in[2];
    const float* src   = (const float*)d_in[3];
    const float* qkv_w = (const float*)d_in[6];
    const float* qkv_b = (const float*)d_in[7];
    const float* out_w = (const float*)d_in[8];
    const float* out_b = (const float*)d_in[9];
    const float* ln2_w = (const float*)d_in[10];
    const float* ln2_b = (const float*)d_in[11];
    const float* val_w = (const float*)d_in[12];
    const float* val_b = (const float*)d_in[13];
    const float* off_w = (const float*)d_in[14];
    const float* off_b = (const float*)d_in[15];
    const float* aw_w  = (const float*)d_in[16];
    const float* aw_b  = (const float*)d_in[17];
    const float* op_w  = (const float*)d_in[18];
    const float* op_b  = (const float*)d_in[19];
    const float* ln1_w = (const float*)d_in[20];
    const float* ln1_b = (const float*)d_in[21];
    const float* w1    = (const float*)d_in[22];
    const float* b1    = (const float*)d_in[23];
    const float* w2    = (const float*)d_in[24];
    const float* b2    = (const float*)d_in[25];
    const float* ln3_w = (const float*)d_in[26];
    const float* ln3_b = (const float*)d_in[27];

    float* ws    = (float*)d_ws;
    float* value = ws;                       // 106352*256
    float* buf1  = value + 27226112;         // 7200*1024 (qh|kh, ffn hidden)
    float* vhb   = buf1 + 7372800;
    float* buf3  = vhb + 1843200;
    float* buf4  = buf3 + 1843200;
    float* buf5  = buf4 + 1843200;
    float* t1b   = buf5 + 1843200;
    float* awb   = t1b + 1843200;            // 7200*128
    float* outp  = (float*)d_out;

    dim3 blk(256);
    // 1. q = tgt + query_pos -> buf4
    add_kernel<<<dim3(1800), blk, 0, stream>>>(tgt, qpos, buf4, MQ * Dm / 4);
    // 2. [qh|kh] -> buf1 (ldc 512)
    sgemm<0><<<dim3((MQ + 63) / 64, 512 / 64), blk, 0, stream>>>(MQ, 512, Dm, buf4, Dm, qkv_w, 768, qkv_b, buf1, 512);
    // 3. vh -> vhb
    sgemm<0><<<dim3((MQ + 63) / 64, 256 / 64), blk, 0, stream>>>(MQ, 256, Dm, tgt, Dm, qkv_w + 512, 768, qkv_b + 512, vhb, 256);
    // 4. self-attention -> buf3
    flash_attn<<<dim3(15, NHm, Bm), blk, 0, stream>>>(buf1, vhb, buf3);
    // 5. sa proj -> buf5
    sgemm<0><<<dim3((MQ + 63) / 64, 256 / 64), blk, 0, stream>>>(MQ, 256, Dm, buf3, Dm, out_w, 256, out_b, buf5, 256);
    // 6. t1 = LN(tgt + sa; ln2) -> t1b
    add_ln_kernel<<<dim3(MQ), blk, 0, stream>>>(tgt, buf5, ln2_w, ln2_b, t1b);
    // 7. q2 = t1 + query_pos -> buf4
    add_kernel<<<dim3(1800), blk, 0, stream>>>(t1b, qpos, buf4, MQ * Dm / 4);
    // 8. value = src @ val_w + val_b -> value
    sgemm<0><<<dim3((MV + 63) / 64, 256 / 64), blk, 0, stream>>>(MV, 256, Dm, src, Dm, val_w, 256, val_b, value, 256);
    // 9. off -> buf3
    sgemm<0><<<dim3((MQ + 63) / 64, 256 / 64), blk, 0, stream>>>(MQ, 256, Dm, buf4, Dm, off_w, 256, off_b, buf3, 256);
    // 10. aw logits -> awb
    sgemm<0><<<dim3((MQ + 63) / 64, 128 / 64), blk, 0, stream>>>(MQ, 128, Dm, buf4, Dm, aw_w, 128, aw_b, awb, 128);
    // 11. msdeform sampling -> vhb
    msdeform_kernel<<<dim3(MQ), blk, 0, stream>>>(value, refp, buf3, awb, vhb);
    // 12. op proj -> buf5
    sgemm<0><<<dim3((MQ + 63) / 64, 256 / 64), blk, 0, stream>>>(MQ, 256, Dm, vhb, Dm, op_w, 256, op_b, buf5, 256);
    // 13. t2 = LN(t1 + ca; ln1) -> buf4
    add_ln_kernel<<<dim3(MQ), blk, 0, stream>>>(t1b, buf5, ln1_w, ln1_b, buf4);
    // 14. ffn hidden = relu(t2 @ w1 + b1) -> buf1
    sgemm<1><<<dim3((MQ + 63) / 64, DFFNm / 64), blk, 0, stream>>>(MQ, DFFNm, Dm, buf4, Dm, w1, DFFNm, b1, buf1, DFFNm);
    // 15. ff = hidden @ w2 + b2 -> buf5
    sgemm<0><<<dim3((MQ + 63) / 64, 256 / 64), blk, 0, stream>>>(MQ, 256, DFFNm, buf1, DFFNm, w2, 256, b2, buf5, 256);
    // 16. out = LN(t2 + ff; ln3) -> d_out
    add_ln_kernel<<<dim3(MQ), blk, 0, stream>>>(buf4, buf5, ln3_w, ln3_b, outp);
}

// Round 3
// 529.496 us; speedup vs baseline: 3.3031x; 1.4718x over previous
//
#include <hip/hip_runtime.h>
#include <math.h>

#define Dm    256
#define NHm   8
#define DHm   32
#define NLEVm 4
#define NPTSm 4
#define DFFNm 1024
#define Bm    8
#define LQm   900
#define LENm  13294
#define MQ    (Bm * LQm)      // 7200
#define MV    (Bm * LENm)     // 106352
#define MQP   7296            // MQ padded to 128
#define MVP   106368          // MV padded to 128

typedef __attribute__((ext_vector_type(8))) short short8;   // 8 bf16 (4 VGPRs)
typedef __attribute__((ext_vector_type(4))) float f32x4;    // MFMA acc

__device__ __forceinline__ unsigned short f2bf(float f) {
    unsigned int b = __float_as_uint(f);
    unsigned int r = (b + 0x7FFFu + ((b >> 16) & 1u)) >> 16;
    return (unsigned short)r;
}
__device__ __forceinline__ float bf2f(unsigned short u) {
    return __uint_as_float(((unsigned int)u) << 16);
}

// -------------------- fp32 -> bf16 convert (optionally add), zero-pad tail ----
__global__ __launch_bounds__(256) void cvt_bf(const float* __restrict__ a,
                                              unsigned short* __restrict__ o,
                                              int n4, int n4pad) {
    int i = blockIdx.x * blockDim.x + threadIdx.x;
    int stride = gridDim.x * blockDim.x;
    for (; i < n4pad; i += stride) {
        ushort4 u;
        if (i < n4) {
            float4 x = reinterpret_cast<const float4*>(a)[i];
            u.x = f2bf(x.x); u.y = f2bf(x.y); u.z = f2bf(x.z); u.w = f2bf(x.w);
        } else {
            u.x = u.y = u.z = u.w = 0;
        }
        reinterpret_cast<ushort4*>(o)[i] = u;
    }
}

__global__ __launch_bounds__(256) void add_bf(const float* __restrict__ a,
                                              const float* __restrict__ b,
                                              unsigned short* __restrict__ o,
                                              int n4, int n4pad) {
    int i = blockIdx.x * blockDim.x + threadIdx.x;
    int stride = gridDim.x * blockDim.x;
    for (; i < n4pad; i += stride) {
        ushort4 u;
        if (i < n4) {
            float4 x = reinterpret_cast<const float4*>(a)[i];
            float4 y = reinterpret_cast<const float4*>(b)[i];
            u.x = f2bf(x.x + y.x); u.y = f2bf(x.y + y.y);
            u.z = f2bf(x.z + y.z); u.w = f2bf(x.w + y.w);
        } else {
            u.x = u.y = u.z = u.w = 0;
        }
        reinterpret_cast<ushort4*>(o)[i] = u;
    }
}

// -------------------- weight transpose+convert: BT[n][k] = bf16(W[k][n]) ----
__global__ __launch_bounds__(256) void wt_kernel(const float* __restrict__ W,
                                                 unsigned short* __restrict__ BT,
                                                 int N, int K) {
    int n = blockIdx.x;
    int k = blockIdx.y * 256 + threadIdx.x;
    BT[(size_t)n * K + k] = f2bf(W[(size_t)k * N + n]);
}

// -------------------- bf16 MFMA GEMM: C = A(MxK) @ BT^T + bias --------------
// A [Mpad][K] bf16 row-major, BT [N][K] bf16 row-major. 128x128 tile, BK=32,
// 256 thr = 4 waves, each wave a 64x64 quadrant (4x4 fragments 16x16x32).
template <int RELU, int OBF>
__global__ __launch_bounds__(256) void bgemm(int M, int N, int K,
        const unsigned short* __restrict__ A,
        const unsigned short* __restrict__ BT,
        const float* __restrict__ bias,
        float* __restrict__ Cf, unsigned short* __restrict__ Cb, int ldc) {
    __shared__ __align__(16) unsigned short As[128 * 32];
    __shared__ __align__(16) unsigned short Bs[128 * 32];
    int t = threadIdx.x;
    int l = t & 63;
    int w = t >> 6;
    int row0 = blockIdx.x * 128, col0 = blockIdx.y * 128;
    int wr = (w >> 1) * 64, wc = (w & 1) * 64;
    f32x4 acc[4][4];
    #pragma unroll
    for (int m = 0; m < 4; ++m)
        #pragma unroll
        for (int n = 0; n < 4; ++n) acc[m][n] = (f32x4){0.f, 0.f, 0.f, 0.f};

    // staging: slot s in [0,512): tile row = s>>2, elem offset (s&3)*8 (16B)
    int s0 = t, s1 = t + 256;
    const unsigned short* Ag = A + (size_t)row0 * K;
    const unsigned short* Bg = BT + (size_t)col0 * K;
    const unsigned short* a0p = Ag + (size_t)(s0 >> 2) * K + (s0 & 3) * 8;
    const unsigned short* a1p = Ag + (size_t)(s1 >> 2) * K + (s1 & 3) * 8;
    const unsigned short* b0p = Bg + (size_t)(s0 >> 2) * K + (s0 & 3) * 8;
    const unsigned short* b1p = Bg + (size_t)(s1 >> 2) * K + (s1 & 3) * 8;

    for (int k0 = 0; k0 < K; k0 += 32) {
        short8 ra0 = *(const short8*)(a0p + k0);
        short8 ra1 = *(const short8*)(a1p + k0);
        short8 rb0 = *(const short8*)(b0p + k0);
        short8 rb1 = *(const short8*)(b1p + k0);
        __syncthreads();   // prior iteration's LDS reads done
        *(short8*)(As + s0 * 8) = ra0;
        *(short8*)(As + s1 * 8) = ra1;
        *(short8*)(Bs + s0 * 8) = rb0;
        *(short8*)(Bs + s1 * 8) = rb1;
        __syncthreads();
        short8 af[4], bfr[4];
        #pragma unroll
        for (int m = 0; m < 4; ++m)
            af[m] = *(const short8*)(As + (wr + m * 16 + (l & 15)) * 32 + (l >> 4) * 8);
        #pragma unroll
        for (int n = 0; n < 4; ++n)
            bfr[n] = *(const short8*)(Bs + (wc + n * 16 + (l & 15)) * 32 + (l >> 4) * 8);
        #pragma unroll
        for (int m = 0; m < 4; ++m)
            #pragma unroll
            for (int n = 0; n < 4; ++n)
                acc[m][n] = __builtin_amdgcn_mfma_f32_16x16x32_bf16(af[m], bfr[n], acc[m][n], 0, 0, 0);
    }

    int cr = (l >> 4) * 4;
    int cc = l & 15;
    #pragma unroll
    for (int m = 0; m < 4; ++m) {
        #pragma unroll
        for (int n = 0; n < 4; ++n) {
            int col = col0 + wc + n * 16 + cc;
            float bv = bias[col];
            #pragma unroll
            for (int j = 0; j < 4; ++j) {
                int r = row0 + wr + m * 16 + cr + j;
                if (r < M) {
                    float v = acc[m][n][j] + bv;
                    if (RELU) v = fmaxf(v, 0.f);
                    if (OBF) Cb[(size_t)r * ldc + col] = f2bf(v);
                    else     Cf[(size_t)r * ldc + col] = v;
                }
            }
        }
    }
}

// -------------------- flash self-attention (fp32 in, bf16 out) --------------
__global__ __launch_bounds__(256) void flash_attn(const float* __restrict__ qk,  // (MQ,512): [qh|kh]
                                                  const float* __restrict__ vh,  // (MQ,256)
                                                  unsigned short* __restrict__ out) { // (MQP,256) bf16
    __shared__ float Qs[64][36];
    __shared__ float Ks[64][36];
    __shared__ float Vs[64][36];
    __shared__ float Ps[64][68];
    __shared__ float ms[64], ls[64], rs[64];

    int t = threadIdx.x;
    int q0 = blockIdx.x * 64;
    int h = blockIdx.y;
    int b = blockIdx.z;
    const float scale = 0.17677669529663687f;

    {
        const float* Qbase = qk + (size_t)(b * LQm + q0) * 512 + h * DHm;
        #pragma unroll
        for (int e = t; e < 512; e += 256) {
            int r = e >> 3, c = e & 7;
            float4 v = make_float4(0.f, 0.f, 0.f, 0.f);
            if (q0 + r < LQm) v = *reinterpret_cast<const float4*>(Qbase + (size_t)r * 512 + c * 4);
            *reinterpret_cast<float4*>(&Qs[r][c * 4]) = v;
        }
    }
    if (t < 64) { ms[t] = -1e30f; ls[t] = 0.f; }

    int qg = t >> 4;
    int kg = t & 15;
    int q_pv = t >> 2;
    int dg = t & 3;
    float acc[8] = {0.f, 0.f, 0.f, 0.f, 0.f, 0.f, 0.f, 0.f};

    for (int k0 = 0; k0 < LQm; k0 += 64) {
        __syncthreads();
        {
            const float* Kbase = qk + (size_t)(b * LQm + k0) * 512 + 256 + h * DHm;
            const float* Vbase = vh + (size_t)(b * LQm + k0) * 256 + h * DHm;
            #pragma unroll
            for (int e = t; e < 512; e += 256) {
                int r = e >> 3, c = e & 7;
                float4 kv4 = make_float4(0.f, 0.f, 0.f, 0.f);
                float4 vv4 = make_float4(0.f, 0.f, 0.f, 0.f);
                if (k0 + r < LQm) {
                    kv4 = *reinterpret_cast<const float4*>(Kbase + (size_t)r * 512 + c * 4);
                    vv4 = *reinterpret_cast<const float4*>(Vbase + (size_t)r * 256 + c * 4);
                }
                *reinterpret_cast<float4*>(&Ks[r][c * 4]) = kv4;
                *reinterpret_cast<float4*>(&Vs[r][c * 4]) = vv4;
            }
        }
        __syncthreads();

        float s[4][4] = {};
        for (int d4 = 0; d4 < 8; d4++) {
            float4 qv[4], kv[4];
            #pragma unroll
            for (int i = 0; i < 4; i++) qv[i] = *reinterpret_cast<const float4*>(&Qs[qg * 4 + i][d4 * 4]);
            #pragma unroll
            for (int j = 0; j < 4; j++) kv[j] = *reinterpret_cast<const float4*>(&Ks[kg + 16 * j][d4 * 4]);
            #pragma unroll
            for (int i = 0; i < 4; i++)
                #pragma unroll
                for (int j = 0; j < 4; j++) {
                    s[i][j] += qv[i].x * kv[j].x + qv[i].y * kv[j].y +
                               qv[i].z * kv[j].z + qv[i].w * kv[j].w;
                }
        }
        #pragma unroll
        for (int i = 0; i < 4; i++)
            #pragma unroll
            for (int j = 0; j < 4; j++) {
                s[i][j] *= scale;
                if (k0 + kg + 16 * j >= LQm) s[i][j] = -1e30f;
            }

        float tm[4], mold[4], newm[4];
        #pragma unroll
        for (int i = 0; i < 4; i++)
            tm[i] = fmaxf(fmaxf(s[i][0], s[i][1]), fmaxf(s[i][2], s[i][3]));
        #pragma unroll
        for (int msk = 1; msk <= 8; msk <<= 1) {
            #pragma unroll
            for (int i = 0; i < 4; i++) tm[i] = fmaxf(tm[i], __shfl_xor(tm[i], msk));
        }
        #pragma unroll
        for (int i = 0; i < 4; i++) {
            mold[i] = ms[qg * 4 + i];
            newm[i] = fmaxf(mold[i], tm[i]);
        }
        float p[4][4], psum[4];
        #pragma unroll
        for (int i = 0; i < 4; i++) {
            psum[i] = 0.f;
            #pragma unroll
            for (int j = 0; j < 4; j++) {
                p[i][j] = __expf(s[i][j] - newm[i]);
                psum[i] += p[i][j];
            }
        }
        #pragma unroll
        for (int msk = 1; msk <= 8; msk <<= 1) {
            #pragma unroll
            for (int i = 0; i < 4; i++) psum[i] += __shfl_xor(psum[i], msk);
        }
        if (kg == 0) {
            #pragma unroll
            for (int i = 0; i < 4; i++) {
                int q = qg * 4 + i;
                float r_ = __expf(mold[i] - newm[i]);
                rs[q] = r_;
                ls[q] = ls[q] * r_ + psum[i];
                ms[q] = newm[i];
            }
        }
        #pragma unroll
        for (int i = 0; i < 4; i++)
            #pragma unroll
            for (int j = 0; j < 4; j++)
                Ps[qg * 4 + i][kg + 16 * j] = p[i][j];
        __syncthreads();

        float rsc = rs[q_pv];
        #pragma unroll
        for (int n = 0; n < 8; n++) acc[n] *= rsc;
        for (int kk4 = 0; kk4 < 16; kk4++) {
            float4 p4 = *reinterpret_cast<const float4*>(&Ps[q_pv][kk4 * 4]);
            #pragma unroll
            for (int u = 0; u < 4; u++) {
                float pv = (&p4.x)[u];
                float4 v0 = *reinterpret_cast<const float4*>(&Vs[kk4 * 4 + u][dg * 8]);
                float4 v1 = *reinterpret_cast<const float4*>(&Vs[kk4 * 4 + u][dg * 8 + 4]);
                acc[0] += pv * v0.x; acc[1] += pv * v0.y; acc[2] += pv * v0.z; acc[3] += pv * v0.w;
                acc[4] += pv * v1.x; acc[5] += pv * v1.y; acc[6] += pv * v1.z; acc[7] += pv * v1.w;
            }
        }
    }
    __syncthreads();
    if (q0 + q_pv < LQm) {
        float inv = 1.0f / ls[q_pv];
        unsigned short* ob = out + (size_t)(b * LQm + q0 + q_pv) * 256 + h * DHm + dg * 8;
        ushort4 u0, u1;
        u0.x = f2bf(acc[0] * inv); u0.y = f2bf(acc[1] * inv);
        u0.z = f2bf(acc[2] * inv); u0.w = f2bf(acc[3] * inv);
        u1.x = f2bf(acc[4] * inv); u1.y = f2bf(acc[5] * inv);
        u1.z = f2bf(acc[6] * inv); u1.w = f2bf(acc[7] * inv);
        *reinterpret_cast<ushort4*>(ob) = u0;
        *reinterpret_cast<ushort4*>(ob + 4) = u1;
    }
}

// -------------------- fused residual add + LayerNorm ------------------------
template <int DUAL>
__global__ __launch_bounds__(256) void add_ln_kernel(const float* __restrict__ x,
                                                     const float* __restrict__ r,
                                                     const float* __restrict__ w,
                                                     const float* __restrict__ b,
                                                     float* __restrict__ out,
                                                     unsigned short* __restrict__ outb) {
    int row = blockIdx.x;
    int t = threadIdx.x;
    __shared__ float red[256];
    float v = x[(size_t)row * Dm + t] + r[(size_t)row * Dm + t];
    red[t] = v;
    __syncthreads();
    for (int s = 128; s > 0; s >>= 1) {
        if (t < s) red[t] += red[t + s];
        __syncthreads();
    }
    float mean = red[0] * (1.0f / Dm);
    __syncthreads();
    float dv = v - mean;
    red[t] = dv * dv;
    __syncthreads();
    for (int s = 128; s > 0; s >>= 1) {
        if (t < s) red[t] += red[t + s];
        __syncthreads();
    }
    float var = red[0] * (1.0f / Dm);
    float res = dv * rsqrtf(var + 1e-5f) * w[t] + b[t];
    out[(size_t)row * Dm + t] = res;
    if (DUAL) outb[(size_t)row * Dm + t] = f2bf(res);
}

// -------------------- ms-deformable attention sampling (bf16 value) ---------
__global__ __launch_bounds__(256) void msdeform_kernel(const unsigned short* __restrict__ value, // (MVP,256) bf16
                                                       const float* __restrict__ ref,
                                                       const float* __restrict__ off,
                                                       const float* __restrict__ awl,
                                                       unsigned short* __restrict__ out) { // (MQP,256) bf16
    const int HL[4] = {100, 50, 25, 13};
    const int WL[4] = {100, 50, 25, 13};
    const int ST[4] = {0, 10000, 12500, 13125};
    int m = blockIdx.x;
    int b = m / LQm;
    int t = threadIdx.x;
    __shared__ float lsx[NHm][16], lsy[NHm][16], wgt[NHm][16];
    if (t < 128) {
        int h = t >> 4, i = t & 15;
        int lev = i >> 2, pt = i & 3;
        float rx = ref[((size_t)m * NLEVm + lev) * 2 + 0];
        float ry = ref[((size_t)m * NLEVm + lev) * 2 + 1];
        float ox = off[(size_t)m * 256 + (size_t)((h * NLEVm + lev) * NPTSm + pt) * 2 + 0];
        float oy = off[(size_t)m * 256 + (size_t)((h * NLEVm + lev) * NPTSm + pt) * 2 + 1];
        float Wf = (float)WL[lev], Hf = (float)HL[lev];
        lsx[h][i] = (rx + ox / Wf) * Wf - 0.5f;
        lsy[h][i] = (ry + oy / Hf) * Hf - 0.5f;
        wgt[h][i] = awl[(size_t)m * 128 + h * 16 + i];
    }
    __syncthreads();
    if (t < NHm) {
        int h = t;
        float mx = -1e30f;
        #pragma unroll
        for (int i = 0; i < 16; i++) mx = fmaxf(mx, wgt[h][i]);
        float s = 0.f;
        #pragma unroll
        for (int i = 0; i < 16; i++) { float e = __expf(wgt[h][i] - mx); wgt[h][i] = e; s += e; }
        float inv = 1.0f / s;
        #pragma unroll
        for (int i = 0; i < 16; i++) wgt[h][i] *= inv;
    }
    __syncthreads();
    int h = t >> 5, d = t & 31;
    float acc = 0.f;
    #pragma unroll
    for (int i = 0; i < 16; i++) {
        int lev = i >> 2;
        float lx = lsx[h][i], ly = lsy[h][i];
        int Wl = WL[lev], Hl = HL[lev];
        float x0f = floorf(lx), y0f = floorf(ly);
        float fx = lx - x0f, fy = ly - y0f;
        int x0 = (int)x0f, y0 = (int)y0f;
        float aw = wgt[h][i];
        const unsigned short* vbase = value + ((size_t)(b * LENm + ST[lev])) * 256 + h * DHm + d;
        #pragma unroll
        for (int c = 0; c < 4; c++) {
            int dx = c & 1, dy = c >> 1;
            int xi = x0 + dx, yi = y0 + dy;
            if (xi >= 0 && xi < Wl && yi >= 0 && yi < Hl) {
                float wgt2 = (dx ? fx : 1.0f - fx) * (dy ? fy : 1.0f - fy);
                acc += aw * wgt2 * bf2f(vbase[(size_t)(yi * Wl + xi) * 256]);
            }
        }
    }
    out[(size_t)m * 256 + h * DHm + d] = f2bf(acc);
}

// ------------------------------------------------------------------
extern "C" void kernel_launch(void* const* d_in, const int* in_sizes, int n_in,
                              void* d_out, int out_size, void* d_ws, size_t ws_size,
                              hipStream_t stream) {
    const float* tgt   = (const float*)d_in[0];
    const float* qpos  = (const float*)d_in[1];
    const float* refp  = (const float*)d_in[2];
    const float* src   = (const float*)d_in[3];
    const float* qkv_w = (const float*)d_in[6];
    const float* qkv_b = (const float*)d_in[7];
    const float* out_w = (const float*)d_in[8];
    const float* out_b = (const float*)d_in[9];
    const float* ln2_w = (const float*)d_in[10];
    const float* ln2_b = (const float*)d_in[11];
    const float* val_w = (const float*)d_in[12];
    const float* val_b = (const float*)d_in[13];
    const float* off_w = (const float*)d_in[14];
    const float* off_b = (const float*)d_in[15];
    const float* aw_w  = (const float*)d_in[16];
    const float* aw_b  = (const float*)d_in[17];
    const float* op_w  = (const float*)d_in[18];
    const float* op_b  = (const float*)d_in[19];
    const float* ln1_w = (const float*)d_in[20];
    const float* ln1_b = (const float*)d_in[21];
    const float* w1    = (const float*)d_in[22];
    const float* b1    = (const float*)d_in[23];
    const float* w2    = (const float*)d_in[24];
    const float* b2    = (const float*)d_in[25];
    const float* ln3_w = (const float*)d_in[26];
    const float* ln3_b = (const float*)d_in[27];

    char* base = (char*)d_ws;
    unsigned short* value_bf  = (unsigned short*)(base);                      // MVP*256*2 = 54,460,416
    unsigned short* src_bf    = (unsigned short*)(base + 54460416);           // 54,460,416
    unsigned short* hidden_bf = src_bf;                                       // reuse after value gemm
    unsigned short* t2_bf     = (unsigned short*)(base + 54460416 + 14942208);
    float* qkh  = (float*)(base + 108920832);                                 // 14,745,600
    float* offb = qkh;                                                        // reuse after flash
    float* awb  = (float*)(base + 108920832 + 7372800);
    float* S1   = (float*)(base + 123666432);                                 // 7,372,800 (vh/sa/op/ff)
    float* t1   = (float*)(base + 131039232);
    float* t2   = (float*)(base + 138412032);
    unsigned short* Qbf     = (unsigned short*)(base + 145784832);            // q_bf then t1pq_bf
    unsigned short* tgt_bf  = (unsigned short*)(base + 149520384);
    unsigned short* attn_bf = (unsigned short*)(base + 153255936);
    unsigned short* ca_bf   = (unsigned short*)(base + 156991488);
    unsigned short* BT_qkv  = (unsigned short*)(base + 160727040);            // [768][256]
    unsigned short* BT_out  = BT_qkv + 768 * 256;                             // [256][256]
    unsigned short* BT_val  = BT_out + 256 * 256;
    unsigned short* BT_off  = BT_val + 256 * 256;
    unsigned short* BT_aw   = BT_off + 256 * 256;                             // [128][256]
    unsigned short* BT_op   = BT_aw + 128 * 256;
    unsigned short* BT_w1   = BT_op + 256 * 256;                              // [1024][256]
    unsigned short* BT_w2   = BT_w1 + 1024 * 256;                             // [256][1024]
    float* outp = (float*)d_out;

    dim3 blk(256);
    // weight transposes (bf16 [N][K])
    wt_kernel<<<dim3(768, 1), blk, 0, stream>>>(qkv_w, BT_qkv, 768, 256);
    wt_kernel<<<dim3(256, 1), blk, 0, stream>>>(out_w, BT_out, 256, 256);
    wt_kernel<<<dim3(256, 1), blk, 0, stream>>>(val_w, BT_val, 256, 256);
    wt_kernel<<<dim3(256, 1), blk, 0, stream>>>(off_w, BT_off, 256, 256);
    wt_kernel<<<dim3(128, 1), blk, 0, stream>>>(aw_w,  BT_aw,  128, 256);
    wt_kernel<<<dim3(256, 1), blk, 0, stream>>>(op_w,  BT_op,  256, 256);
    wt_kernel<<<dim3(1024, 1), blk, 0, stream>>>(w1,   BT_w1, 1024, 256);
    wt_kernel<<<dim3(256, 4), blk, 0, stream>>>(w2,    BT_w2,  256, 1024);

    // input conversions
    cvt_bf<<<dim3(1824), blk, 0, stream>>>(tgt, tgt_bf, MQ * Dm / 4, MQP * Dm / 4);
    add_bf<<<dim3(1824), blk, 0, stream>>>(tgt, qpos, Qbf, MQ * Dm / 4, MQP * Dm / 4);

    // qkh = q @ Wqk + b  -> qkh fp32 (ldc 512)
    bgemm<0, 0><<<dim3(57, 4), blk, 0, stream>>>(MQ, 512, 256, Qbf, BT_qkv, qkv_b, qkh, nullptr, 512);
    // vh = tgt @ Wv + b  -> S1 fp32
    bgemm<0, 0><<<dim3(57, 2), blk, 0, stream>>>(MQ, 256, 256, tgt_bf, BT_qkv + 512 * 256, qkv_b + 512, S1, nullptr, 256);
    // self-attention -> attn_bf
    flash_attn<<<dim3(15, NHm, Bm), blk, 0, stream>>>(qkh, S1, attn_bf);
    // sa proj -> S1
    bgemm<0, 0><<<dim3(57, 2), blk, 0, stream>>>(MQ, 256, 256, attn_bf, BT_out, out_b, S1, nullptr, 256);
    // t1 = LN(tgt + sa; ln2)
    add_ln_kernel<0><<<dim3(MQ), blk, 0, stream>>>(tgt, S1, ln2_w, ln2_b, t1, nullptr);
    // t1pq_bf = t1 + qpos
    add_bf<<<dim3(1824), blk, 0, stream>>>(t1, qpos, Qbf, MQ * Dm / 4, MQP * Dm / 4);
    // src -> bf16
    cvt_bf<<<dim3(2048), blk, 0, stream>>>(src, src_bf, MV * Dm / 4, MVP * Dm / 4);
    // value = src @ val_w + val_b -> value_bf (bf16 out)
    bgemm<0, 1><<<dim3(831, 2), blk, 0, stream>>>(MV, 256, 256, src_bf, BT_val, val_b, nullptr, value_bf, 256);
    // off -> offb fp32
    bgemm<0, 0><<<dim3(57, 2), blk, 0, stream>>>(MQ, 256, 256, Qbf, BT_off, off_b, offb, nullptr, 256);
    // aw logits -> awb fp32
    bgemm<0, 0><<<dim3(57, 1), blk, 0, stream>>>(MQ, 128, 256, Qbf, BT_aw, aw_b, awb, nullptr, 128);
    // msdeform -> ca_bf
    msdeform_kernel<<<dim3(MQ), blk, 0, stream>>>(value_bf, refp, offb, awb, ca_bf);
    // op proj -> S1
    bgemm<0, 0><<<dim3(57, 2), blk, 0, stream>>>(MQ, 256, 256, ca_bf, BT_op, op_b, S1, nullptr, 256);
    // t2 = LN(t1 + ca; ln1) -> t2 fp32 + t2_bf
    add_ln_kernel<1><<<dim3(MQ), blk, 0, stream>>>(t1, S1, ln1_w, ln1_b, t2, t2_bf);
    // hidden = relu(t2 @ w1 + b1) -> hidden_bf
    bgemm<1, 1><<<dim3(57, 8), blk, 0, stream>>>(MQ, DFFNm, 256, t2_bf, BT_w1, b1, nullptr, hidden_bf, DFFNm);
    // ff = hidden @ w2 + b2 -> S1
    bgemm<0, 0><<<dim3(57, 2), blk, 0, stream>>>(MQ, 256, 1024, hidden_bf, BT_w2, b2, S1, nullptr, 256);
    // out = LN(t2 + ff; ln3)
    add_ln_kernel<0><<<dim3(MQ), blk, 0, stream>>>(t2, S1, ln3_w, ln3_b, outp, nullptr);
}

// Round 5
// 399.421 us; speedup vs baseline: 4.3788x; 1.3257x over previous
//
#include <hip/hip_runtime.h>
#include <math.h>

#define Dm    256
#define NHm   8
#define DHm   32
#define NLEVm 4
#define NPTSm 4
#define DFFNm 1024
#define Bm    8
#define LQm   900
#define LENm  13294
#define MQ    (Bm * LQm)      // 7200
#define MV    (Bm * LENm)     // 106352
#define MQP   7296            // MQ padded to 128
#define MVP   106368          // MV padded to 128
#define LQP   960             // keys padded to 15*64

typedef __attribute__((ext_vector_type(8))) short short8;   // 8 bf16 (4 VGPRs)
typedef __attribute__((ext_vector_type(4))) float f32x4;    // MFMA acc

__device__ __forceinline__ unsigned short f2bf(float f) {
    unsigned int b = __float_as_uint(f);
    unsigned int r = (b + 0x7FFFu + ((b >> 16) & 1u)) >> 16;
    return (unsigned short)r;
}
__device__ __forceinline__ float bf2f(unsigned short u) {
    return __uint_as_float(((unsigned int)u) << 16);
}

// -------------------- fp32 -> bf16 convert, zero-pad tail ----
__global__ __launch_bounds__(256) void cvt_bf(const float* __restrict__ a,
                                              unsigned short* __restrict__ o,
                                              int n4, int n4pad) {
    int i = blockIdx.x * blockDim.x + threadIdx.x;
    int stride = gridDim.x * blockDim.x;
    for (; i < n4pad; i += stride) {
        ushort4 u;
        if (i < n4) {
            float4 x = reinterpret_cast<const float4*>(a)[i];
            u.x = f2bf(x.x); u.y = f2bf(x.y); u.z = f2bf(x.z); u.w = f2bf(x.w);
        } else {
            u.x = u.y = u.z = u.w = 0;
        }
        reinterpret_cast<ushort4*>(o)[i] = u;
    }
}

__global__ __launch_bounds__(256) void add_bf(const float* __restrict__ a,
                                              const float* __restrict__ b,
                                              unsigned short* __restrict__ o,
                                              int n4, int n4pad) {
    int i = blockIdx.x * blockDim.x + threadIdx.x;
    int stride = gridDim.x * blockDim.x;
    for (; i < n4pad; i += stride) {
        ushort4 u;
        if (i < n4) {
            float4 x = reinterpret_cast<const float4*>(a)[i];
            float4 y = reinterpret_cast<const float4*>(b)[i];
            u.x = f2bf(x.x + y.x); u.y = f2bf(x.y + y.y);
            u.z = f2bf(x.z + y.z); u.w = f2bf(x.w + y.w);
        } else {
            u.x = u.y = u.z = u.w = 0;
        }
        reinterpret_cast<ushort4*>(o)[i] = u;
    }
}

// -------------------- zero Vt pad key-columns [900,960) --------------------
// Vt rows = B*256 = 2048, cols = LQP. Unwritten pad cols would otherwise hold
// leftover fp32 halves across graph replays -> bf16 NaN -> 0*NaN poisons PV.
__global__ __launch_bounds__(256) void vtpad_kernel(unsigned short* __restrict__ vt) {
    int i = blockIdx.x * 256 + threadIdx.x;       // 2048*60 = 122880
    int row = i / 60, c = 900 + (i % 60);
    vt[(size_t)row * LQP + c] = 0;
}

// -------------------- weight transpose+convert: BT[n][k] = bf16(W[k][n]) ----
__global__ __launch_bounds__(256) void wt_kernel(const float* __restrict__ W,
                                                 unsigned short* __restrict__ BT,
                                                 int N, int K) {
    int n = blockIdx.x;
    int k = blockIdx.y * 256 + threadIdx.x;
    BT[(size_t)n * K + k] = f2bf(W[(size_t)k * N + n]);
}

// -------------------- bf16 MFMA GEMM: C = A(MxK) @ BT^T + bias --------------
// OBF: 0 = fp32 out, 1 = bf16 out, 2 = bf16 V-transposed out (Vt[(b*8+h)*32+d][LQP])
template <int RELU, int OBF>
__global__ __launch_bounds__(256) void bgemm(int M, int N, int K,
        const unsigned short* __restrict__ A,
        const unsigned short* __restrict__ BT,
        const float* __restrict__ bias,
        float* __restrict__ Cf, unsigned short* __restrict__ Cb, int ldc) {
    __shared__ __align__(16) unsigned short As[128 * 32];
    __shared__ __align__(16) unsigned short Bs[128 * 32];
    int t = threadIdx.x;
    int l = t & 63;
    int w = t >> 6;
    int row0 = blockIdx.x * 128, col0 = blockIdx.y * 128;
    int wr = (w >> 1) * 64, wc = (w & 1) * 64;
    f32x4 acc[4][4];
    #pragma unroll
    for (int m = 0; m < 4; ++m)
        #pragma unroll
        for (int n = 0; n < 4; ++n) acc[m][n] = (f32x4){0.f, 0.f, 0.f, 0.f};

    int s0 = t, s1 = t + 256;
    const unsigned short* Ag = A + (size_t)row0 * K;
    const unsigned short* Bg = BT + (size_t)col0 * K;
    const unsigned short* a0p = Ag + (size_t)(s0 >> 2) * K + (s0 & 3) * 8;
    const unsigned short* a1p = Ag + (size_t)(s1 >> 2) * K + (s1 & 3) * 8;
    const unsigned short* b0p = Bg + (size_t)(s0 >> 2) * K + (s0 & 3) * 8;
    const unsigned short* b1p = Bg + (size_t)(s1 >> 2) * K + (s1 & 3) * 8;

    for (int k0 = 0; k0 < K; k0 += 32) {
        short8 ra0 = *(const short8*)(a0p + k0);
        short8 ra1 = *(const short8*)(a1p + k0);
        short8 rb0 = *(const short8*)(b0p + k0);
        short8 rb1 = *(const short8*)(b1p + k0);
        __syncthreads();
        *(short8*)(As + s0 * 8) = ra0;
        *(short8*)(As + s1 * 8) = ra1;
        *(short8*)(Bs + s0 * 8) = rb0;
        *(short8*)(Bs + s1 * 8) = rb1;
        __syncthreads();
        short8 af[4], bfr[4];
        #pragma unroll
        for (int m = 0; m < 4; ++m)
            af[m] = *(const short8*)(As + (wr + m * 16 + (l & 15)) * 32 + (l >> 4) * 8);
        #pragma unroll
        for (int n = 0; n < 4; ++n)
            bfr[n] = *(const short8*)(Bs + (wc + n * 16 + (l & 15)) * 32 + (l >> 4) * 8);
        #pragma unroll
        for (int m = 0; m < 4; ++m)
            #pragma unroll
            for (int n = 0; n < 4; ++n)
                acc[m][n] = __builtin_amdgcn_mfma_f32_16x16x32_bf16(af[m], bfr[n], acc[m][n], 0, 0, 0);
    }

    int cr = (l >> 4) * 4;
    int cc = l & 15;
    #pragma unroll
    for (int m = 0; m < 4; ++m) {
        #pragma unroll
        for (int n = 0; n < 4; ++n) {
            int col = col0 + wc + n * 16 + cc;
            float bv = bias[col];
            if (OBF == 2) {
                int r0 = row0 + wr + m * 16 + cr;   // multiple of 4; 900%4==0
                if (r0 < M) {
                    int bb = r0 / 900;
                    int q = r0 - bb * 900;
                    ushort4 u;
                    u.x = f2bf(acc[m][n][0] + bv);
                    u.y = f2bf(acc[m][n][1] + bv);
                    u.z = f2bf(acc[m][n][2] + bv);
                    u.w = f2bf(acc[m][n][3] + bv);
                    *reinterpret_cast<ushort4*>(Cb + ((size_t)(bb * 256 + col)) * LQP + q) = u;
                }
            } else {
                #pragma unroll
                for (int j = 0; j < 4; ++j) {
                    int r = row0 + wr + m * 16 + cr + j;
                    if (r < M) {
                        float v = acc[m][n][j] + bv;
                        if (RELU) v = fmaxf(v, 0.f);
                        if (OBF) Cb[(size_t)r * ldc + col] = f2bf(v);
                        else     Cf[(size_t)r * ldc + col] = v;
                    }
                }
            }
        }
    }
}

// -------------------- MFMA flash self-attention ------------------------------
// grid (15, NH, B); 256 thr = 4 waves, each wave owns 16 q-rows. No barriers.
// qk: [MQP][512] bf16 ([qh|kh]); vt: [B*256][LQP] bf16 (row = (b*8+h)*32+d)
__global__ __launch_bounds__(256) void flash_mfma(const unsigned short* __restrict__ qk,
                                                  const unsigned short* __restrict__ vt,
                                                  unsigned short* __restrict__ out) {
    __shared__ unsigned short P_lds[4][16][72];
    int t = threadIdx.x;
    int l = t & 63, w = t >> 6;
    int lr = l & 15, lg = l >> 4;
    int qt = blockIdx.x, h = blockIdx.y, b = blockIdx.z;
    const float scale = 0.17677669529663687f;

    // Q fragment: A[row=lr][k=lg*8+j] -> row q = qt*64+w*16+lr
    short8 qf = *(const short8*)(qk + (size_t)(b * LQm + qt * 64 + w * 16 + lr) * 512 + h * 32 + lg * 8);

    f32x4 accO[2];
    accO[0] = (f32x4){0.f, 0.f, 0.f, 0.f};
    accO[1] = (f32x4){0.f, 0.f, 0.f, 0.f};
    float mrow[4] = {-1e30f, -1e30f, -1e30f, -1e30f};
    float lrow[4] = {0.f, 0.f, 0.f, 0.f};
    const f32x4 zero = (f32x4){0.f, 0.f, 0.f, 0.f};
    const unsigned short* vtb = vt + ((size_t)(b * 256 + h * 32)) * LQP;

    for (int kt = 0; kt < 15; ++kt) {
        int k0 = kt * 64;
        // QK^T: 4 MFMAs -> S[16q][64k]
        f32x4 sfr[4];
        #pragma unroll
        for (int ks = 0; ks < 4; ++ks) {
            short8 kf = *(const short8*)(qk + (size_t)(b * LQm + k0 + ks * 16 + lr) * 512 + 256 + h * 32 + lg * 8);
            sfr[ks] = __builtin_amdgcn_mfma_f32_16x16x32_bf16(qf, kf, zero, 0, 0, 0);
        }
        float sv[4][4];
        #pragma unroll
        for (int ks = 0; ks < 4; ++ks) {
            bool valid = (k0 + ks * 16 + lr) < LQm;
            #pragma unroll
            for (int j = 0; j < 4; ++j)
                sv[ks][j] = valid ? sfr[ks][j] * scale : -1e30f;
        }
        float tm[4], newm[4], rr[4], ps[4];
        #pragma unroll
        for (int j = 0; j < 4; ++j)
            tm[j] = fmaxf(fmaxf(sv[0][j], sv[1][j]), fmaxf(sv[2][j], sv[3][j]));
        #pragma unroll
        for (int msk = 1; msk <= 8; msk <<= 1) {
            #pragma unroll
            for (int j = 0; j < 4; ++j) tm[j] = fmaxf(tm[j], __shfl_xor(tm[j], msk));
        }
        #pragma unroll
        for (int j = 0; j < 4; ++j) {
            newm[j] = fmaxf(mrow[j], tm[j]);
            rr[j] = __expf(mrow[j] - newm[j]);
            mrow[j] = newm[j];
            ps[j] = 0.f;
        }
        float pv[4][4];
        #pragma unroll
        for (int ks = 0; ks < 4; ++ks)
            #pragma unroll
            for (int j = 0; j < 4; ++j) {
                pv[ks][j] = __expf(sv[ks][j] - newm[j]);
                ps[j] += pv[ks][j];
            }
        #pragma unroll
        for (int msk = 1; msk <= 8; msk <<= 1) {
            #pragma unroll
            for (int j = 0; j < 4; ++j) ps[j] += __shfl_xor(ps[j], msk);
        }
        #pragma unroll
        for (int j = 0; j < 4; ++j) lrow[j] = lrow[j] * rr[j] + ps[j];
        #pragma unroll
        for (int n = 0; n < 2; ++n)
            #pragma unroll
            for (int j = 0; j < 4; ++j) accO[n][j] *= rr[j];
        // P -> LDS (C-layout -> A-layout transpose), wave-private
        #pragma unroll
        for (int ks = 0; ks < 4; ++ks)
            #pragma unroll
            for (int j = 0; j < 4; ++j)
                P_lds[w][lg * 4 + j][ks * 16 + lr] = f2bf(pv[ks][j]);
        // PV: 2 k-halves x 2 d-halves
        #pragma unroll
        for (int kh2 = 0; kh2 < 2; ++kh2) {
            short8 pf = *(const short8*)(&P_lds[w][lr][kh2 * 32 + lg * 8]);
            #pragma unroll
            for (int n = 0; n < 2; ++n) {
                short8 vf = *(const short8*)(vtb + (size_t)(n * 16 + lr) * LQP + k0 + kh2 * 32 + lg * 8);
                accO[n] = __builtin_amdgcn_mfma_f32_16x16x32_bf16(pf, vf, accO[n], 0, 0, 0);
            }
        }
    }
    float inv[4];
    #pragma unroll
    for (int j = 0; j < 4; ++j) inv[j] = 1.0f / lrow[j];
    #pragma unroll
    for (int n = 0; n < 2; ++n)
        #pragma unroll
        for (int j = 0; j < 4; ++j) {
            int q = qt * 64 + w * 16 + lg * 4 + j;
            if (q < LQm)
                out[(size_t)(b * LQm + q) * 256 + h * 32 + n * 16 + lr] = f2bf(accO[n][j] * inv[j]);
        }
}

// -------------------- fused residual add + LayerNorm ------------------------
template <int DUAL>
__global__ __launch_bounds__(256) void add_ln_kernel(const float* __restrict__ x,
                                                     const float* __restrict__ r,
                                                     const float* __restrict__ w,
                                                     const float* __restrict__ b,
                                                     float* __restrict__ out,
                                                     unsigned short* __restrict__ outb) {
    int row = blockIdx.x;
    int t = threadIdx.x;
    __shared__ float red[256];
    float v = x[(size_t)row * Dm + t] + r[(size_t)row * Dm + t];
    red[t] = v;
    __syncthreads();
    for (int s = 128; s > 0; s >>= 1) {
        if (t < s) red[t] += red[t + s];
        __syncthreads();
    }
    float mean = red[0] * (1.0f / Dm);
    __syncthreads();
    float dv = v - mean;
    red[t] = dv * dv;
    __syncthreads();
    for (int s = 128; s > 0; s >>= 1) {
        if (t < s) red[t] += red[t + s];
        __syncthreads();
    }
    float var = red[0] * (1.0f / Dm);
    float res = dv * rsqrtf(var + 1e-5f) * w[t] + b[t];
    out[(size_t)row * Dm + t] = res;
    if (DUAL) outb[(size_t)row * Dm + t] = f2bf(res);
}

// -------------------- ms-deformable attention sampling (bf16 value) ---------
__global__ __launch_bounds__(256) void msdeform_kernel(const unsigned short* __restrict__ value,
                                                       const float* __restrict__ ref,
                                                       const float* __restrict__ off,
                                                       const float* __restrict__ awl,
                                                       unsigned short* __restrict__ out) {
    const int HL[4] = {100, 50, 25, 13};
    const int WL[4] = {100, 50, 25, 13};
    const int ST[4] = {0, 10000, 12500, 13125};
    int m = blockIdx.x;
    int b = m / LQm;
    int t = threadIdx.x;
    __shared__ float lsx[NHm][16], lsy[NHm][16], wgt[NHm][16];
    if (t < 128) {
        int h = t >> 4, i = t & 15;
        int lev = i >> 2, pt = i & 3;
        float rx = ref[((size_t)m * NLEVm + lev) * 2 + 0];
        float ry = ref[((size_t)m * NLEVm + lev) * 2 + 1];
        float ox = off[(size_t)m * 256 + (size_t)((h * NLEVm + lev) * NPTSm + pt) * 2 + 0];
        float oy = off[(size_t)m * 256 + (size_t)((h * NLEVm + lev) * NPTSm + pt) * 2 + 1];
        float Wf = (float)WL[lev], Hf = (float)HL[lev];
        lsx[h][i] = (rx + ox / Wf) * Wf - 0.5f;
        lsy[h][i] = (ry + oy / Hf) * Hf - 0.5f;
        wgt[h][i] = awl[(size_t)m * 128 + h * 16 + i];
    }
    __syncthreads();
    if (t < NHm) {
        int h = t;
        float mx = -1e30f;
        #pragma unroll
        for (int i = 0; i < 16; i++) mx = fmaxf(mx, wgt[h][i]);
        float s = 0.f;
        #pragma unroll
        for (int i = 0; i < 16; i++) { float e = __expf(wgt[h][i] - mx); wgt[h][i] = e; s += e; }
        float inv = 1.0f / s;
        #pragma unroll
        for (int i = 0; i < 16; i++) wgt[h][i] *= inv;
    }
    __syncthreads();
    int h = t >> 5, d = t & 31;
    float acc = 0.f;
    #pragma unroll
    for (int i = 0; i < 16; i++) {
        int lev = i >> 2;
        float lx = lsx[h][i], ly = lsy[h][i];
        int Wl = WL[lev], Hl = HL[lev];
        float x0f = floorf(lx), y0f = floorf(ly);
        float fx = lx - x0f, fy = ly - y0f;
        int x0 = (int)x0f, y0 = (int)y0f;
        float aw = wgt[h][i];
        const unsigned short* vbase = value + ((size_t)(b * LENm + ST[lev])) * 256 + h * DHm + d;
        #pragma unroll
        for (int c = 0; c < 4; c++) {
            int dx = c & 1, dy = c >> 1;
            int xi = x0 + dx, yi = y0 + dy;
            if (xi >= 0 && xi < Wl && yi >= 0 && yi < Hl) {
                float wgt2 = (dx ? fx : 1.0f - fx) * (dy ? fy : 1.0f - fy);
                acc += aw * wgt2 * bf2f(vbase[(size_t)(yi * Wl + xi) * 256]);
            }
        }
    }
    out[(size_t)m * 256 + h * DHm + d] = f2bf(acc);
}

// ------------------------------------------------------------------
extern "C" void kernel_launch(void* const* d_in, const int* in_sizes, int n_in,
                              void* d_out, int out_size, void* d_ws, size_t ws_size,
                              hipStream_t stream) {
    const float* tgt   = (const float*)d_in[0];
    const float* qpos  = (const float*)d_in[1];
    const float* refp  = (const float*)d_in[2];
    const float* src   = (const float*)d_in[3];
    const float* qkv_w = (const float*)d_in[6];
    const float* qkv_b = (const float*)d_in[7];
    const float* out_w = (const float*)d_in[8];
    const float* out_b = (const float*)d_in[9];
    const float* ln2_w = (const float*)d_in[10];
    const float* ln2_b = (const float*)d_in[11];
    const float* val_w = (const float*)d_in[12];
    const float* val_b = (const float*)d_in[13];
    const float* off_w = (const float*)d_in[14];
    const float* off_b = (const float*)d_in[15];
    const float* aw_w  = (const float*)d_in[16];
    const float* aw_b  = (const float*)d_in[17];
    const float* op_w  = (const float*)d_in[18];
    const float* op_b  = (const float*)d_in[19];
    const float* ln1_w = (const float*)d_in[20];
    const float* ln1_b = (const float*)d_in[21];
    const float* w1    = (const float*)d_in[22];
    const float* b1    = (const float*)d_in[23];
    const float* w2    = (const float*)d_in[24];
    const float* b2    = (const float*)d_in[25];
    const float* ln3_w = (const float*)d_in[26];
    const float* ln3_b = (const float*)d_in[27];

    char* base = (char*)d_ws;
    unsigned short* value_bf  = (unsigned short*)(base);                      // 54,460,416
    unsigned short* src_bf    = (unsigned short*)(base + 54460416);           // 54,460,416
    unsigned short* hidden_bf = src_bf;                                       // reuse after value gemm
    unsigned short* t2_bf     = (unsigned short*)(base + 54460416 + 14942208);
    // region A: qk_bf (gemm->flash), later offb (off-gemm->msdeform)
    unsigned short* qk_bf = (unsigned short*)(base + 108920832);              // MQP*512*2
    float* offb = (float*)(base + 108920832);
    float* awb  = (float*)(base + 108920832 + 7372800);
    // region B: Vt (vh-gemm->flash), later S1 fp32 (sa/op/ff)
    unsigned short* Vt = (unsigned short*)(base + 123666432);                 // 8*256*960*2
    float* S1   = (float*)(base + 123666432);
    float* t1   = (float*)(base + 131039232);
    float* t2   = (float*)(base + 138412032);
    unsigned short* Qbf     = (unsigned short*)(base + 145784832);
    unsigned short* tgt_bf  = (unsigned short*)(base + 149520384);
    unsigned short* attn_bf = (unsigned short*)(base + 153255936);
    unsigned short* ca_bf   = (unsigned short*)(base + 156991488);
    unsigned short* BT_qkv  = (unsigned short*)(base + 160727040);            // [768][256]
    unsigned short* BT_out  = BT_qkv + 768 * 256;
    unsigned short* BT_val  = BT_out + 256 * 256;
    unsigned short* BT_off  = BT_val + 256 * 256;
    unsigned short* BT_aw   = BT_off + 256 * 256;
    unsigned short* BT_op   = BT_aw + 128 * 256;
    unsigned short* BT_w1   = BT_op + 256 * 256;
    unsigned short* BT_w2   = BT_w1 + 1024 * 256;
    float* outp = (float*)d_out;

    dim3 blk(256);
    wt_kernel<<<dim3(768, 1), blk, 0, stream>>>(qkv_w, BT_qkv, 768, 256);
    wt_kernel<<<dim3(256, 1), blk, 0, stream>>>(out_w, BT_out, 256, 256);
    wt_kernel<<<dim3(256, 1), blk, 0, stream>>>(val_w, BT_val, 256, 256);
    wt_kernel<<<dim3(256, 1), blk, 0, stream>>>(off_w, BT_off, 256, 256);
    wt_kernel<<<dim3(128, 1), blk, 0, stream>>>(aw_w,  BT_aw,  128, 256);
    wt_kernel<<<dim3(256, 1), blk, 0, stream>>>(op_w,  BT_op,  256, 256);
    wt_kernel<<<dim3(1024, 1), blk, 0, stream>>>(w1,   BT_w1, 1024, 256);
    wt_kernel<<<dim3(256, 4), blk, 0, stream>>>(w2,    BT_w2,  256, 1024);

    cvt_bf<<<dim3(1824), blk, 0, stream>>>(tgt, tgt_bf, MQ * Dm / 4, MQP * Dm / 4);
    add_bf<<<dim3(1824), blk, 0, stream>>>(tgt, qpos, Qbf, MQ * Dm / 4, MQP * Dm / 4);

    // qkh (bf16) = q @ Wqk + b -> qk_bf [MQP][512]
    bgemm<0, 1><<<dim3(57, 4), blk, 0, stream>>>(MQ, 512, 256, Qbf, BT_qkv, qkv_b, nullptr, qk_bf, 512);
    // Vt (bf16, transposed) = tgt @ Wv + b
    bgemm<0, 2><<<dim3(57, 2), blk, 0, stream>>>(MQ, 256, 256, tgt_bf, BT_qkv + 512 * 256, qkv_b + 512, nullptr, Vt, 256);
    // zero Vt pad key-columns (disjoint from gemm's cols; needed every call)
    vtpad_kernel<<<dim3(480), blk, 0, stream>>>(Vt);
    // self-attention (MFMA) -> attn_bf
    flash_mfma<<<dim3(15, NHm, Bm), blk, 0, stream>>>(qk_bf, Vt, attn_bf);
    // sa proj -> S1 (overwrites Vt region; flash done)
    bgemm<0, 0><<<dim3(57, 2), blk, 0, stream>>>(MQ, 256, 256, attn_bf, BT_out, out_b, S1, nullptr, 256);
    // t1 = LN(tgt + sa; ln2)
    add_ln_kernel<0><<<dim3(MQ), blk, 0, stream>>>(tgt, S1, ln2_w, ln2_b, t1, nullptr);
    // t1pq_bf = t1 + qpos
    add_bf<<<dim3(1824), blk, 0, stream>>>(t1, qpos, Qbf, MQ * Dm / 4, MQP * Dm / 4);
    // src -> bf16
    cvt_bf<<<dim3(2048), blk, 0, stream>>>(src, src_bf, MV * Dm / 4, MVP * Dm / 4);
    // value = src @ val_w + val_b -> value_bf
    bgemm<0, 1><<<dim3(831, 2), blk, 0, stream>>>(MV, 256, 256, src_bf, BT_val, val_b, nullptr, value_bf, 256);
    // off -> offb fp32 (overwrites qk_bf region; flash done)
    bgemm<0, 0><<<dim3(57, 2), blk, 0, stream>>>(MQ, 256, 256, Qbf, BT_off, off_b, offb, nullptr, 256);
    // aw logits -> awb
    bgemm<0, 0><<<dim3(57, 1), blk, 0, stream>>>(MQ, 128, 256, Qbf, BT_aw, aw_b, awb, nullptr, 128);
    // msdeform -> ca_bf
    msdeform_kernel<<<dim3(MQ), blk, 0, stream>>>(value_bf, refp, offb, awb, ca_bf);
    // op proj -> S1
    bgemm<0, 0><<<dim3(57, 2), blk, 0, stream>>>(MQ, 256, 256, ca_bf, BT_op, op_b, S1, nullptr, 256);
    // t2 = LN(t1 + ca; ln1) -> t2 + t2_bf
    add_ln_kernel<1><<<dim3(MQ), blk, 0, stream>>>(t1, S1, ln1_w, ln1_b, t2, t2_bf);
    // hidden = relu(t2 @ w1 + b1) -> hidden_bf
    bgemm<1, 1><<<dim3(57, 8), blk, 0, stream>>>(MQ, DFFNm, 256, t2_bf, BT_w1, b1, nullptr, hidden_bf, DFFNm);
    // ff = hidden @ w2 + b2 -> S1
    bgemm<0, 0><<<dim3(57, 2), blk, 0, stream>>>(MQ, 256, 1024, hidden_bf, BT_w2, b2, S1, nullptr, 256);
    // out = LN(t2 + ff; ln3)
    add_ln_kernel<0><<<dim3(MQ), blk, 0, stream>>>(t2, S1, ln3_w, ln3_b, outp, nullptr);
}

// Round 6
// 307.270 us; speedup vs baseline: 5.6920x; 1.2999x over previous
//
#include <hip/hip_runtime.h>
#include <math.h>

#define Dm    256
#define NHm   8
#define DHm   32
#define NLEVm 4
#define NPTSm 4
#define DFFNm 1024
#define Bm    8
#define LQm   900
#define LENm  13294
#define MQ    (Bm * LQm)      // 7200
#define MV    (Bm * LENm)     // 106352
#define MQP   7296            // MQ padded to 128
#define MVP   106368          // MV padded to 128
#define LQP   960             // keys padded to 15*64

typedef __attribute__((ext_vector_type(8))) short short8;   // 8 bf16 (4 VGPRs)
typedef __attribute__((ext_vector_type(4))) float f32x4;    // MFMA acc

__device__ __forceinline__ unsigned short f2bf(float f) {
    unsigned int b = __float_as_uint(f);
    unsigned int r = (b + 0x7FFFu + ((b >> 16) & 1u)) >> 16;
    return (unsigned short)r;
}
__device__ __forceinline__ float bf2f(unsigned short u) {
    return __uint_as_float(((unsigned int)u) << 16);
}

// -------------------- prep: tgt_bf = bf16(tgt); Qbf = bf16(tgt+qpos) --------
__global__ __launch_bounds__(256) void prep0(const float* __restrict__ tgt,
                                             const float* __restrict__ qpos,
                                             unsigned short* __restrict__ tgtb,
                                             unsigned short* __restrict__ qb,
                                             int n4, int n4pad) {
    int i = blockIdx.x * blockDim.x + threadIdx.x;
    int stride = gridDim.x * blockDim.x;
    for (; i < n4pad; i += stride) {
        ushort4 ut, uq;
        if (i < n4) {
            float4 x = reinterpret_cast<const float4*>(tgt)[i];
            float4 y = reinterpret_cast<const float4*>(qpos)[i];
            ut.x = f2bf(x.x); ut.y = f2bf(x.y); ut.z = f2bf(x.z); ut.w = f2bf(x.w);
            uq.x = f2bf(x.x + y.x); uq.y = f2bf(x.y + y.y);
            uq.z = f2bf(x.z + y.z); uq.w = f2bf(x.w + y.w);
        } else {
            ut.x = ut.y = ut.z = ut.w = 0;
            uq.x = uq.y = uq.z = uq.w = 0;
        }
        reinterpret_cast<ushort4*>(tgtb)[i] = ut;
        reinterpret_cast<ushort4*>(qb)[i] = uq;
    }
}

// -------------------- zero Vt pad key-columns [900,960) --------------------
__global__ __launch_bounds__(256) void vtpad_kernel(unsigned short* __restrict__ vt) {
    int i = blockIdx.x * 256 + threadIdx.x;       // 2048*60 = 122880
    int row = i / 60, c = 900 + (i % 60);
    vt[(size_t)row * LQP + c] = 0;
}

// -------------------- tiled weight transpose: BT[n][k] = bf16(W[k][n]) ------
// grid (N/64, K/64), 256 thr, coalesced reads + LDS transpose.
__global__ __launch_bounds__(256) void wt_tiled(const float* __restrict__ W,
                                                unsigned short* __restrict__ BT,
                                                int N, int K) {
    __shared__ float tile[64][65];
    int n0 = blockIdx.x * 64, k0 = blockIdx.y * 64;
    int t = threadIdx.x;
    #pragma unroll
    for (int r0 = 0; r0 < 64; r0 += 16) {
        int r = r0 + (t >> 4);
        int c = (t & 15) * 4;
        float4 v = *reinterpret_cast<const float4*>(W + (size_t)(k0 + r) * N + n0 + c);
        tile[r][c + 0] = v.x; tile[r][c + 1] = v.y; tile[r][c + 2] = v.z; tile[r][c + 3] = v.w;
    }
    __syncthreads();
    #pragma unroll
    for (int s = t; s < 512; s += 256) {
        int r = s >> 3, c8 = (s & 7) * 8;
        short8 u;
        #pragma unroll
        for (int j = 0; j < 8; ++j) u[j] = (short)f2bf(tile[c8 + j][r]);
        *reinterpret_cast<short8*>(BT + (size_t)(n0 + r) * K + k0 + c8) = u;
    }
}

// -------------------- bf16 MFMA GEMM: C = A(MxK) @ BT^T + bias --------------
// OBF: 0 = fp32 out, 1 = bf16 out, 2 = bf16 V-transposed out (Vt)
template <int RELU, int OBF>
__global__ __launch_bounds__(256) void bgemm(int M, int N, int K,
        const unsigned short* __restrict__ A,
        const unsigned short* __restrict__ BT,
        const float* __restrict__ bias,
        float* __restrict__ Cf, unsigned short* __restrict__ Cb, int ldc) {
    __shared__ __align__(16) unsigned short As[128 * 32];
    __shared__ __align__(16) unsigned short Bs[128 * 32];
    int t = threadIdx.x;
    int l = t & 63;
    int w = t >> 6;
    int row0 = blockIdx.x * 128, col0 = blockIdx.y * 128;
    int wr = (w >> 1) * 64, wc = (w & 1) * 64;
    f32x4 acc[4][4];
    #pragma unroll
    for (int m = 0; m < 4; ++m)
        #pragma unroll
        for (int n = 0; n < 4; ++n) acc[m][n] = (f32x4){0.f, 0.f, 0.f, 0.f};

    int s0 = t, s1 = t + 256;
    const unsigned short* Ag = A + (size_t)row0 * K;
    const unsigned short* Bg = BT + (size_t)col0 * K;
    const unsigned short* a0p = Ag + (size_t)(s0 >> 2) * K + (s0 & 3) * 8;
    const unsigned short* a1p = Ag + (size_t)(s1 >> 2) * K + (s1 & 3) * 8;
    const unsigned short* b0p = Bg + (size_t)(s0 >> 2) * K + (s0 & 3) * 8;
    const unsigned short* b1p = Bg + (size_t)(s1 >> 2) * K + (s1 & 3) * 8;

    for (int k0 = 0; k0 < K; k0 += 32) {
        short8 ra0 = *(const short8*)(a0p + k0);
        short8 ra1 = *(const short8*)(a1p + k0);
        short8 rb0 = *(const short8*)(b0p + k0);
        short8 rb1 = *(const short8*)(b1p + k0);
        __syncthreads();
        *(short8*)(As + s0 * 8) = ra0;
        *(short8*)(As + s1 * 8) = ra1;
        *(short8*)(Bs + s0 * 8) = rb0;
        *(short8*)(Bs + s1 * 8) = rb1;
        __syncthreads();
        short8 af[4], bfr[4];
        #pragma unroll
        for (int m = 0; m < 4; ++m)
            af[m] = *(const short8*)(As + (wr + m * 16 + (l & 15)) * 32 + (l >> 4) * 8);
        #pragma unroll
        for (int n = 0; n < 4; ++n)
            bfr[n] = *(const short8*)(Bs + (wc + n * 16 + (l & 15)) * 32 + (l >> 4) * 8);
        #pragma unroll
        for (int m = 0; m < 4; ++m)
            #pragma unroll
            for (int n = 0; n < 4; ++n)
                acc[m][n] = __builtin_amdgcn_mfma_f32_16x16x32_bf16(af[m], bfr[n], acc[m][n], 0, 0, 0);
    }

    int cr = (l >> 4) * 4;
    int cc = l & 15;
    #pragma unroll
    for (int m = 0; m < 4; ++m) {
        #pragma unroll
        for (int n = 0; n < 4; ++n) {
            int col = col0 + wc + n * 16 + cc;
            float bv = bias[col];
            if (OBF == 2) {
                int r0 = row0 + wr + m * 16 + cr;   // multiple of 4; 900%4==0
                if (r0 < M) {
                    int bb = r0 / 900;
                    int q = r0 - bb * 900;
                    ushort4 u;
                    u.x = f2bf(acc[m][n][0] + bv);
                    u.y = f2bf(acc[m][n][1] + bv);
                    u.z = f2bf(acc[m][n][2] + bv);
                    u.w = f2bf(acc[m][n][3] + bv);
                    *reinterpret_cast<ushort4*>(Cb + ((size_t)(bb * 256 + col)) * LQP + q) = u;
                }
            } else {
                #pragma unroll
                for (int j = 0; j < 4; ++j) {
                    int r = row0 + wr + m * 16 + cr + j;
                    if (r < M) {
                        float v = acc[m][n][j] + bv;
                        if (RELU) v = fmaxf(v, 0.f);
                        if (OBF) Cb[(size_t)r * ldc + col] = f2bf(v);
                        else     Cf[(size_t)r * ldc + col] = v;
                    }
                }
            }
        }
    }
}

// -------------------- value GEMM: A is fp32 (converted in staging) ----------
__global__ __launch_bounds__(256) void bgemm_vf(int M, int N, int K,
        const float* __restrict__ A,
        const unsigned short* __restrict__ BT,
        const float* __restrict__ bias,
        unsigned short* __restrict__ Cb, int ldc) {
    __shared__ __align__(16) unsigned short As[128 * 32];
    __shared__ __align__(16) unsigned short Bs[128 * 32];
    int t = threadIdx.x;
    int l = t & 63;
    int w = t >> 6;
    int row0 = blockIdx.x * 128, col0 = blockIdx.y * 128;
    int wr = (w >> 1) * 64, wc = (w & 1) * 64;
    f32x4 acc[4][4];
    #pragma unroll
    for (int m = 0; m < 4; ++m)
        #pragma unroll
        for (int n = 0; n < 4; ++n) acc[m][n] = (f32x4){0.f, 0.f, 0.f, 0.f};

    int s0 = t, s1 = t + 256;
    int r0c = min(row0 + (s0 >> 2), M - 1);     // clamp: src has no pad rows
    int r1c = min(row0 + (s1 >> 2), M - 1);
    const float* a0p = A + (size_t)r0c * K + (s0 & 3) * 8;
    const float* a1p = A + (size_t)r1c * K + (s1 & 3) * 8;
    const unsigned short* Bg = BT + (size_t)col0 * K;
    const unsigned short* b0p = Bg + (size_t)(s0 >> 2) * K + (s0 & 3) * 8;
    const unsigned short* b1p = Bg + (size_t)(s1 >> 2) * K + (s1 & 3) * 8;

    for (int k0 = 0; k0 < K; k0 += 32) {
        float4 fa0 = *(const float4*)(a0p + k0);
        float4 fa1 = *(const float4*)(a0p + k0 + 4);
        float4 fb0 = *(const float4*)(a1p + k0);
        float4 fb1 = *(const float4*)(a1p + k0 + 4);
        short8 rb0 = *(const short8*)(b0p + k0);
        short8 rb1 = *(const short8*)(b1p + k0);
        short8 ra0, ra1;
        ra0[0] = (short)f2bf(fa0.x); ra0[1] = (short)f2bf(fa0.y);
        ra0[2] = (short)f2bf(fa0.z); ra0[3] = (short)f2bf(fa0.w);
        ra0[4] = (short)f2bf(fa1.x); ra0[5] = (short)f2bf(fa1.y);
        ra0[6] = (short)f2bf(fa1.z); ra0[7] = (short)f2bf(fa1.w);
        ra1[0] = (short)f2bf(fb0.x); ra1[1] = (short)f2bf(fb0.y);
        ra1[2] = (short)f2bf(fb0.z); ra1[3] = (short)f2bf(fb0.w);
        ra1[4] = (short)f2bf(fb1.x); ra1[5] = (short)f2bf(fb1.y);
        ra1[6] = (short)f2bf(fb1.z); ra1[7] = (short)f2bf(fb1.w);
        __syncthreads();
        *(short8*)(As + s0 * 8) = ra0;
        *(short8*)(As + s1 * 8) = ra1;
        *(short8*)(Bs + s0 * 8) = rb0;
        *(short8*)(Bs + s1 * 8) = rb1;
        __syncthreads();
        short8 af[4], bfr[4];
        #pragma unroll
        for (int m = 0; m < 4; ++m)
            af[m] = *(const short8*)(As + (wr + m * 16 + (l & 15)) * 32 + (l >> 4) * 8);
        #pragma unroll
        for (int n = 0; n < 4; ++n)
            bfr[n] = *(const short8*)(Bs + (wc + n * 16 + (l & 15)) * 32 + (l >> 4) * 8);
        #pragma unroll
        for (int m = 0; m < 4; ++m)
            #pragma unroll
            for (int n = 0; n < 4; ++n)
                acc[m][n] = __builtin_amdgcn_mfma_f32_16x16x32_bf16(af[m], bfr[n], acc[m][n], 0, 0, 0);
    }

    int cr = (l >> 4) * 4;
    int cc = l & 15;
    #pragma unroll
    for (int m = 0; m < 4; ++m) {
        #pragma unroll
        for (int n = 0; n < 4; ++n) {
            int col = col0 + wc + n * 16 + cc;
            float bv = bias[col];
            #pragma unroll
            for (int j = 0; j < 4; ++j) {
                int r = row0 + wr + m * 16 + cr + j;
                if (r < M)
                    Cb[(size_t)r * ldc + col] = f2bf(acc[m][n][j] + bv);
            }
        }
    }
}

// -------------------- MFMA flash self-attention ------------------------------
__global__ __launch_bounds__(256) void flash_mfma(const unsigned short* __restrict__ qk,
                                                  const unsigned short* __restrict__ vt,
                                                  unsigned short* __restrict__ out) {
    __shared__ unsigned short P_lds[4][16][72];
    int t = threadIdx.x;
    int l = t & 63, w = t >> 6;
    int lr = l & 15, lg = l >> 4;
    int qt = blockIdx.x, h = blockIdx.y, b = blockIdx.z;
    const float scale = 0.17677669529663687f;

    short8 qf = *(const short8*)(qk + (size_t)(b * LQm + qt * 64 + w * 16 + lr) * 512 + h * 32 + lg * 8);

    f32x4 accO[2];
    accO[0] = (f32x4){0.f, 0.f, 0.f, 0.f};
    accO[1] = (f32x4){0.f, 0.f, 0.f, 0.f};
    float mrow[4] = {-1e30f, -1e30f, -1e30f, -1e30f};
    float lrow[4] = {0.f, 0.f, 0.f, 0.f};
    const f32x4 zero = (f32x4){0.f, 0.f, 0.f, 0.f};
    const unsigned short* vtb = vt + ((size_t)(b * 256 + h * 32)) * LQP;

    for (int kt = 0; kt < 15; ++kt) {
        int k0 = kt * 64;
        f32x4 sfr[4];
        #pragma unroll
        for (int ks = 0; ks < 4; ++ks) {
            short8 kf = *(const short8*)(qk + (size_t)(b * LQm + k0 + ks * 16 + lr) * 512 + 256 + h * 32 + lg * 8);
            sfr[ks] = __builtin_amdgcn_mfma_f32_16x16x32_bf16(qf, kf, zero, 0, 0, 0);
        }
        float sv[4][4];
        #pragma unroll
        for (int ks = 0; ks < 4; ++ks) {
            bool valid = (k0 + ks * 16 + lr) < LQm;
            #pragma unroll
            for (int j = 0; j < 4; ++j)
                sv[ks][j] = valid ? sfr[ks][j] * scale : -1e30f;
        }
        float tm[4], newm[4], rr[4], ps[4];
        #pragma unroll
        for (int j = 0; j < 4; ++j)
            tm[j] = fmaxf(fmaxf(sv[0][j], sv[1][j]), fmaxf(sv[2][j], sv[3][j]));
        #pragma unroll
        for (int msk = 1; msk <= 8; msk <<= 1) {
            #pragma unroll
            for (int j = 0; j < 4; ++j) tm[j] = fmaxf(tm[j], __shfl_xor(tm[j], msk));
        }
        #pragma unroll
        for (int j = 0; j < 4; ++j) {
            newm[j] = fmaxf(mrow[j], tm[j]);
            rr[j] = __expf(mrow[j] - newm[j]);
            mrow[j] = newm[j];
            ps[j] = 0.f;
        }
        float pv[4][4];
        #pragma unroll
        for (int ks = 0; ks < 4; ++ks)
            #pragma unroll
            for (int j = 0; j < 4; ++j) {
                pv[ks][j] = __expf(sv[ks][j] - newm[j]);
                ps[j] += pv[ks][j];
            }
        #pragma unroll
        for (int msk = 1; msk <= 8; msk <<= 1) {
            #pragma unroll
            for (int j = 0; j < 4; ++j) ps[j] += __shfl_xor(ps[j], msk);
        }
        #pragma unroll
        for (int j = 0; j < 4; ++j) lrow[j] = lrow[j] * rr[j] + ps[j];
        #pragma unroll
        for (int n = 0; n < 2; ++n)
            #pragma unroll
            for (int j = 0; j < 4; ++j) accO[n][j] *= rr[j];
        #pragma unroll
        for (int ks = 0; ks < 4; ++ks)
            #pragma unroll
            for (int j = 0; j < 4; ++j)
                P_lds[w][lg * 4 + j][ks * 16 + lr] = f2bf(pv[ks][j]);
        #pragma unroll
        for (int kh2 = 0; kh2 < 2; ++kh2) {
            short8 pf = *(const short8*)(&P_lds[w][lr][kh2 * 32 + lg * 8]);
            #pragma unroll
            for (int n = 0; n < 2; ++n) {
                short8 vf = *(const short8*)(vtb + (size_t)(n * 16 + lr) * LQP + k0 + kh2 * 32 + lg * 8);
                accO[n] = __builtin_amdgcn_mfma_f32_16x16x32_bf16(pf, vf, accO[n], 0, 0, 0);
            }
        }
    }
    float inv[4];
    #pragma unroll
    for (int j = 0; j < 4; ++j) inv[j] = 1.0f / lrow[j];
    #pragma unroll
    for (int n = 0; n < 2; ++n)
        #pragma unroll
        for (int j = 0; j < 4; ++j) {
            int q = qt * 64 + w * 16 + lg * 4 + j;
            if (q < LQm)
                out[(size_t)(b * LQm + q) * 256 + h * 32 + n * 16 + lr] = f2bf(accO[n][j] * inv[j]);
        }
}

// -------------------- fused residual add + LayerNorm (wave per row) ---------
// DUAL: also emit bf16 copy. QP: also emit bf16(res + qpos) (for t1+query_pos).
template <int DUAL, int QP>
__global__ __launch_bounds__(256) void add_ln_kernel(const float* __restrict__ x,
                                                     const float* __restrict__ r,
                                                     const float* __restrict__ w,
                                                     const float* __restrict__ b,
                                                     const float* __restrict__ qpos,
                                                     float* __restrict__ out,
                                                     unsigned short* __restrict__ outb,
                                                     unsigned short* __restrict__ outq) {
    int row = blockIdx.x * 4 + (threadIdx.x >> 6);
    int lane = threadIdx.x & 63;
    size_t i4 = (size_t)row * 64 + lane;
    float4 xv = reinterpret_cast<const float4*>(x)[i4];
    float4 rv = reinterpret_cast<const float4*>(r)[i4];
    float4 v = make_float4(xv.x + rv.x, xv.y + rv.y, xv.z + rv.z, xv.w + rv.w);
    float s = v.x + v.y + v.z + v.w;
    #pragma unroll
    for (int msk = 1; msk <= 32; msk <<= 1) s += __shfl_xor(s, msk);
    float mean = s * (1.0f / Dm);
    float4 dv = make_float4(v.x - mean, v.y - mean, v.z - mean, v.w - mean);
    float sq = dv.x * dv.x + dv.y * dv.y + dv.z * dv.z + dv.w * dv.w;
    #pragma unroll
    for (int msk = 1; msk <= 32; msk <<= 1) sq += __shfl_xor(sq, msk);
    float is = rsqrtf(sq * (1.0f / Dm) + 1e-5f);
    float4 wv = reinterpret_cast<const float4*>(w)[lane];
    float4 bv = reinterpret_cast<const float4*>(b)[lane];
    float4 res = make_float4(dv.x * is * wv.x + bv.x, dv.y * is * wv.y + bv.y,
                             dv.z * is * wv.z + bv.z, dv.w * is * wv.w + bv.w);
    reinterpret_cast<float4*>(out)[i4] = res;
    if (DUAL) {
        ushort4 u;
        u.x = f2bf(res.x); u.y = f2bf(res.y); u.z = f2bf(res.z); u.w = f2bf(res.w);
        reinterpret_cast<ushort4*>(outb)[i4] = u;
    }
    if (QP) {
        float4 qv = reinterpret_cast<const float4*>(qpos)[i4];
        ushort4 u;
        u.x = f2bf(res.x + qv.x); u.y = f2bf(res.y + qv.y);
        u.z = f2bf(res.z + qv.z); u.w = f2bf(res.w + qv.w);
        reinterpret_cast<ushort4*>(outq)[i4] = u;
    }
}

// -------------------- ms-deformable sampling: wave per query ----------------
// grid 1800 x 256thr = 4 queries/block (1 wave each).
__global__ __launch_bounds__(256) void msdeform_kernel(const unsigned short* __restrict__ value,
                                                       const float* __restrict__ ref,
                                                       const float* __restrict__ off,
                                                       const float* __restrict__ awl,
                                                       unsigned short* __restrict__ out) {
    const int HL[4] = {100, 50, 25, 13};
    const int ST[4] = {0, 10000, 12500, 13125};
    __shared__ float lsx[4][128], lsy[4][128], wtab[4][128];
    __shared__ float2 ctab[4][512];
    int wv = threadIdx.x >> 6, lane = threadIdx.x & 63;
    int m = blockIdx.x * 4 + wv;
    int b = m / LQm;

    // phase 1: sampling locations + raw weights (128 (h,i) entries, 2/lane)
    #pragma unroll
    for (int e = lane; e < 128; e += 64) {
        int lev = (e >> 2) & 3;
        float rx = ref[((size_t)m * NLEVm + lev) * 2 + 0];
        float ry = ref[((size_t)m * NLEVm + lev) * 2 + 1];
        float ox = off[(size_t)m * 256 + e * 2 + 0];
        float oy = off[(size_t)m * 256 + e * 2 + 1];
        float Wf = (float)HL[lev];
        lsx[wv][e] = (rx + ox / Wf) * Wf - 0.5f;
        lsy[wv][e] = (ry + oy / Wf) * Wf - 0.5f;
        wtab[wv][e] = awl[(size_t)m * 128 + e];
    }
    __syncthreads();
    // phase 2: per-head softmax over 16 logits
    if (lane < NHm) {
        int h = lane;
        float mx = -1e30f;
        #pragma unroll
        for (int i = 0; i < 16; i++) mx = fmaxf(mx, wtab[wv][h * 16 + i]);
        float s = 0.f;
        #pragma unroll
        for (int i = 0; i < 16; i++) {
            float e = __expf(wtab[wv][h * 16 + i] - mx);
            wtab[wv][h * 16 + i] = e; s += e;
        }
        float inv = 1.0f / s;
        #pragma unroll
        for (int i = 0; i < 16; i++) wtab[wv][h * 16 + i] *= inv;
    }
    __syncthreads();
    // phase 3: corner table (512 corners, 8/lane): global row + fused weight
    #pragma unroll
    for (int j = 0; j < 8; ++j) {
        int e2 = lane * 8 + j;
        int c = e2 & 3, e = e2 >> 2;
        int lev = (e >> 2) & 3;
        int Wl = HL[lev];
        float lx = lsx[wv][e], ly = lsy[wv][e];
        float x0f = floorf(lx), y0f = floorf(ly);
        float fx = lx - x0f, fy = ly - y0f;
        int dx = c & 1, dy = c >> 1;
        int xi = (int)x0f + dx, yi = (int)y0f + dy;
        bool valid = (xi >= 0) && (xi < Wl) && (yi >= 0) && (yi < Wl);
        float wc = valid ? ((dx ? fx : 1.0f - fx) * (dy ? fy : 1.0f - fy)) * wtab[wv][e] : 0.f;
        int xc = min(max(xi, 0), Wl - 1), yc = min(max(yi, 0), Wl - 1);
        int row = b * LENm + ST[lev] + yc * Wl + xc;
        ctab[wv][e2] = make_float2(__int_as_float(row), wc);
    }
    __syncthreads();
    // phase 4: gather. lane = (head, 4-dim group); ushort4 loads.
    int h = lane >> 3, dg = lane & 7;
    const unsigned short* basep = value + h * 32 + dg * 4;
    float a0 = 0.f, a1 = 0.f, a2 = 0.f, a3 = 0.f;
    #pragma unroll
    for (int i = 0; i < 16; ++i) {
        #pragma unroll
        for (int c = 0; c < 4; ++c) {
            float2 cc = ctab[wv][(h * 16 + i) * 4 + c];
            int row = __float_as_int(cc.x);
            float wc = cc.y;
            ushort4 v = *reinterpret_cast<const ushort4*>(basep + (size_t)row * 256);
            a0 += wc * bf2f(v.x); a1 += wc * bf2f(v.y);
            a2 += wc * bf2f(v.z); a3 += wc * bf2f(v.w);
        }
    }
    ushort4 o;
    o.x = f2bf(a0); o.y = f2bf(a1); o.z = f2bf(a2); o.w = f2bf(a3);
    *reinterpret_cast<ushort4*>(out + (size_t)m * 256 + h * 32 + dg * 4) = o;
}

// ------------------------------------------------------------------
extern "C" void kernel_launch(void* const* d_in, const int* in_sizes, int n_in,
                              void* d_out, int out_size, void* d_ws, size_t ws_size,
                              hipStream_t stream) {
    const float* tgt   = (const float*)d_in[0];
    const float* qpos  = (const float*)d_in[1];
    const float* refp  = (const float*)d_in[2];
    const float* src   = (const float*)d_in[3];
    const float* qkv_w = (const float*)d_in[6];
    const float* qkv_b = (const float*)d_in[7];
    const float* out_w = (const float*)d_in[8];
    const float* out_b = (const float*)d_in[9];
    const float* ln2_w = (const float*)d_in[10];
    const float* ln2_b = (const float*)d_in[11];
    const float* val_w = (const float*)d_in[12];
    const float* val_b = (const float*)d_in[13];
    const float* off_w = (const float*)d_in[14];
    const float* off_b = (const float*)d_in[15];
    const float* aw_w  = (const float*)d_in[16];
    const float* aw_b  = (const float*)d_in[17];
    const float* op_w  = (const float*)d_in[18];
    const float* op_b  = (const float*)d_in[19];
    const float* ln1_w = (const float*)d_in[20];
    const float* ln1_b = (const float*)d_in[21];
    const float* w1    = (const float*)d_in[22];
    const float* b1    = (const float*)d_in[23];
    const float* w2    = (const float*)d_in[24];
    const float* b2    = (const float*)d_in[25];
    const float* ln3_w = (const float*)d_in[26];
    const float* ln3_b = (const float*)d_in[27];

    char* base = (char*)d_ws;
    unsigned short* value_bf  = (unsigned short*)(base);                      // 54,460,416
    unsigned short* hidden_bf = (unsigned short*)(base + 54460416);           // MQP*1024*2
    unsigned short* t2_bf     = (unsigned short*)(base + 54460416 + 14942208);
    unsigned short* qk_bf = (unsigned short*)(base + 108920832);              // MQP*512*2
    float* offb = (float*)(base + 108920832);                                 // aliases qk_bf (after flash)
    float* awb  = (float*)(base + 108920832 + 7372800);
    unsigned short* Vt = (unsigned short*)(base + 123666432);                 // 8*256*960*2
    float* S1   = (float*)(base + 123666432);                                 // aliases Vt (after flash)
    float* t1   = (float*)(base + 131039232);
    float* t2   = (float*)(base + 138412032);
    unsigned short* Qbf     = (unsigned short*)(base + 145784832);
    unsigned short* tgt_bf  = (unsigned short*)(base + 149520384);
    unsigned short* attn_bf = (unsigned short*)(base + 153255936);
    unsigned short* ca_bf   = (unsigned short*)(base + 156991488);
    unsigned short* BT_qkv  = (unsigned short*)(base + 160727040);            // [768][256]
    unsigned short* BT_out  = BT_qkv + 768 * 256;
    unsigned short* BT_val  = BT_out + 256 * 256;
    unsigned short* BT_off  = BT_val + 256 * 256;
    unsigned short* BT_aw   = BT_off + 256 * 256;
    unsigned short* BT_op   = BT_aw + 128 * 256;
    unsigned short* BT_w1   = BT_op + 256 * 256;
    unsigned short* BT_w2   = BT_w1 + 1024 * 256;
    float* outp = (float*)d_out;

    dim3 blk(256);
    // tiled weight transposes (bf16 [N][K])
    wt_tiled<<<dim3(12, 4), blk, 0, stream>>>(qkv_w, BT_qkv, 768, 256);
    wt_tiled<<<dim3(4, 4),  blk, 0, stream>>>(out_w, BT_out, 256, 256);
    wt_tiled<<<dim3(4, 4),  blk, 0, stream>>>(val_w, BT_val, 256, 256);
    wt_tiled<<<dim3(4, 4),  blk, 0, stream>>>(off_w, BT_off, 256, 256);
    wt_tiled<<<dim3(2, 4),  blk, 0, stream>>>(aw_w,  BT_aw,  128, 256);
    wt_tiled<<<dim3(4, 4),  blk, 0, stream>>>(op_w,  BT_op,  256, 256);
    wt_tiled<<<dim3(16, 4), blk, 0, stream>>>(w1,    BT_w1, 1024, 256);
    wt_tiled<<<dim3(4, 16), blk, 0, stream>>>(w2,    BT_w2,  256, 1024);

    // tgt_bf + Qbf in one pass
    prep0<<<dim3(1824), blk, 0, stream>>>(tgt, qpos, tgt_bf, Qbf, MQ * Dm / 4, MQP * Dm / 4);

    // qkh (bf16) = q @ Wqk + b -> qk_bf [MQP][512]
    bgemm<0, 1><<<dim3(57, 4), blk, 0, stream>>>(MQ, 512, 256, Qbf, BT_qkv, qkv_b, nullptr, qk_bf, 512);
    // Vt (bf16, transposed) = tgt @ Wv + b
    bgemm<0, 2><<<dim3(57, 2), blk, 0, stream>>>(MQ, 256, 256, tgt_bf, BT_qkv + 512 * 256, qkv_b + 512, nullptr, Vt, 256);
    // zero Vt pad key-columns (every call: graph replays re-dirty S1 alias)
    vtpad_kernel<<<dim3(480), blk, 0, stream>>>(Vt);
    // self-attention (MFMA) -> attn_bf
    flash_mfma<<<dim3(15, NHm, Bm), blk, 0, stream>>>(qk_bf, Vt, attn_bf);
    // sa proj -> S1 (overwrites Vt region; flash done)
    bgemm<0, 0><<<dim3(57, 2), blk, 0, stream>>>(MQ, 256, 256, attn_bf, BT_out, out_b, S1, nullptr, 256);
    // t1 = LN(tgt + sa; ln2); fused Qbf = bf16(t1 + qpos)
    add_ln_kernel<0, 1><<<dim3(1800), blk, 0, stream>>>(tgt, S1, ln2_w, ln2_b, qpos, t1, nullptr, Qbf);
    // value = src @ val_w + val_b -> value_bf (A fp32, converted in staging)
    bgemm_vf<<<dim3(831, 2), blk, 0, stream>>>(MV, 256, 256, src, BT_val, val_b, value_bf, 256);
    // off -> offb fp32 (overwrites qk_bf region; flash done)
    bgemm<0, 0><<<dim3(57, 2), blk, 0, stream>>>(MQ, 256, 256, Qbf, BT_off, off_b, offb, nullptr, 256);
    // aw logits -> awb
    bgemm<0, 0><<<dim3(57, 1), blk, 0, stream>>>(MQ, 128, 256, Qbf, BT_aw, aw_b, awb, nullptr, 128);
    // msdeform -> ca_bf (wave per query)
    msdeform_kernel<<<dim3(1800), blk, 0, stream>>>(value_bf, refp, offb, awb, ca_bf);
    // op proj -> S1
    bgemm<0, 0><<<dim3(57, 2), blk, 0, stream>>>(MQ, 256, 256, ca_bf, BT_op, op_b, S1, nullptr, 256);
    // t2 = LN(t1 + ca; ln1) -> t2 + t2_bf
    add_ln_kernel<1, 0><<<dim3(1800), blk, 0, stream>>>(t1, S1, ln1_w, ln1_b, nullptr, t2, t2_bf, nullptr);
    // hidden = relu(t2 @ w1 + b1) -> hidden_bf
    bgemm<1, 1><<<dim3(57, 8), blk, 0, stream>>>(MQ, DFFNm, 256, t2_bf, BT_w1, b1, nullptr, hidden_bf, DFFNm);
    // ff = hidden @ w2 + b2 -> S1
    bgemm<0, 0><<<dim3(57, 2), blk, 0, stream>>>(MQ, 256, 1024, hidden_bf, BT_w2, b2, S1, nullptr, 256);
    // out = LN(t2 + ff; ln3)
    add_ln_kernel<0, 0><<<dim3(1800), blk, 0, stream>>>(t2, S1, ln3_w, ln3_b, nullptr, outp, nullptr, nullptr);
}

// Round 7
// 290.993 us; speedup vs baseline: 6.0104x; 1.0559x over previous
//
#include <hip/hip_runtime.h>
#include <math.h>

#define Dm    256
#define NHm   8
#define DHm   32
#define NLEVm 4
#define NPTSm 4
#define DFFNm 1024
#define Bm    8
#define LQm   900
#define LENm  13294
#define MQ    (Bm * LQm)      // 7200
#define MV    (Bm * LENm)     // 106352
#define MQP   7296            // MQ padded to 128
#define MVP   106368          // MV padded to 128
#define LQP   960             // keys padded to 15*64

typedef __attribute__((ext_vector_type(8))) short short8;   // 8 bf16 (4 VGPRs)
typedef __attribute__((ext_vector_type(4))) float f32x4;    // MFMA acc

__device__ __forceinline__ unsigned short f2bf(float f) {
    unsigned int b = __float_as_uint(f);
    unsigned int r = (b + 0x7FFFu + ((b >> 16) & 1u)) >> 16;
    return (unsigned short)r;
}
__device__ __forceinline__ float bf2f(unsigned short u) {
    return __uint_as_float(((unsigned int)u) << 16);
}

// -------------------- prep: tgt_bf = bf16(tgt); Qbf = bf16(tgt+qpos) --------
__global__ __launch_bounds__(256) void prep0(const float* __restrict__ tgt,
                                             const float* __restrict__ qpos,
                                             unsigned short* __restrict__ tgtb,
                                             unsigned short* __restrict__ qb,
                                             int n4, int n4pad) {
    int i = blockIdx.x * blockDim.x + threadIdx.x;
    int stride = gridDim.x * blockDim.x;
    for (; i < n4pad; i += stride) {
        ushort4 ut, uq;
        if (i < n4) {
            float4 x = reinterpret_cast<const float4*>(tgt)[i];
            float4 y = reinterpret_cast<const float4*>(qpos)[i];
            ut.x = f2bf(x.x); ut.y = f2bf(x.y); ut.z = f2bf(x.z); ut.w = f2bf(x.w);
            uq.x = f2bf(x.x + y.x); uq.y = f2bf(x.y + y.y);
            uq.z = f2bf(x.z + y.z); uq.w = f2bf(x.w + y.w);
        } else {
            ut.x = ut.y = ut.z = ut.w = 0;
            uq.x = uq.y = uq.z = uq.w = 0;
        }
        reinterpret_cast<ushort4*>(tgtb)[i] = ut;
        reinterpret_cast<ushort4*>(qb)[i] = uq;
    }
}

// -------------------- zero Vt pad key-columns [900,960) --------------------
__global__ __launch_bounds__(256) void vtpad_kernel(unsigned short* __restrict__ vt) {
    int i = blockIdx.x * 256 + threadIdx.x;       // 2048*60 = 122880
    int row = i / 60, c = 900 + (i % 60);
    vt[(size_t)row * LQP + c] = 0;
}

// -------------------- tiled weight transpose: BT[n][k] = bf16(W[k][n]) ------
__global__ __launch_bounds__(256) void wt_tiled(const float* __restrict__ W,
                                                unsigned short* __restrict__ BT,
                                                int N, int K) {
    __shared__ float tile[64][65];
    int n0 = blockIdx.x * 64, k0 = blockIdx.y * 64;
    int t = threadIdx.x;
    #pragma unroll
    for (int r0 = 0; r0 < 64; r0 += 16) {
        int r = r0 + (t >> 4);
        int c = (t & 15) * 4;
        float4 v = *reinterpret_cast<const float4*>(W + (size_t)(k0 + r) * N + n0 + c);
        tile[r][c + 0] = v.x; tile[r][c + 1] = v.y; tile[r][c + 2] = v.z; tile[r][c + 3] = v.w;
    }
    __syncthreads();
    #pragma unroll
    for (int s = t; s < 512; s += 256) {
        int r = s >> 3, c8 = (s & 7) * 8;
        short8 u;
        #pragma unroll
        for (int j = 0; j < 8; ++j) u[j] = (short)f2bf(tile[c8 + j][r]);
        *reinterpret_cast<short8*>(BT + (size_t)(n0 + r) * K + k0 + c8) = u;
    }
}

// -------------------- bf16 MFMA GEMM (software-pipelined staging) -----------
// OBF: 0 = fp32 out, 1 = bf16 out, 2 = bf16 V-transposed out (Vt)
template <int RELU, int OBF>
__global__ __launch_bounds__(256) void bgemm(int M, int N, int K,
        const unsigned short* __restrict__ A,
        const unsigned short* __restrict__ BT,
        const float* __restrict__ bias,
        float* __restrict__ Cf, unsigned short* __restrict__ Cb, int ldc) {
    __shared__ __align__(16) unsigned short As[128 * 32];
    __shared__ __align__(16) unsigned short Bs[128 * 32];
    int t = threadIdx.x;
    int l = t & 63;
    int w = t >> 6;
    int row0 = blockIdx.x * 128, col0 = blockIdx.y * 128;
    int wr = (w >> 1) * 64, wc = (w & 1) * 64;
    f32x4 acc[4][4];
    #pragma unroll
    for (int m = 0; m < 4; ++m)
        #pragma unroll
        for (int n = 0; n < 4; ++n) acc[m][n] = (f32x4){0.f, 0.f, 0.f, 0.f};

    int s0 = t, s1 = t + 256;
    const unsigned short* Ag = A + (size_t)row0 * K;
    const unsigned short* Bg = BT + (size_t)col0 * K;
    const unsigned short* a0p = Ag + (size_t)(s0 >> 2) * K + (s0 & 3) * 8;
    const unsigned short* a1p = Ag + (size_t)(s1 >> 2) * K + (s1 & 3) * 8;
    const unsigned short* b0p = Bg + (size_t)(s0 >> 2) * K + (s0 & 3) * 8;
    const unsigned short* b1p = Bg + (size_t)(s1 >> 2) * K + (s1 & 3) * 8;

    // prologue prefetch
    short8 ra0 = *(const short8*)(a0p);
    short8 ra1 = *(const short8*)(a1p);
    short8 rb0 = *(const short8*)(b0p);
    short8 rb1 = *(const short8*)(b1p);

    for (int k0 = 0; k0 < K; k0 += 32) {
        __syncthreads();   // prior iteration's LDS reads done
        *(short8*)(As + s0 * 8) = ra0;
        *(short8*)(As + s1 * 8) = ra1;
        *(short8*)(Bs + s0 * 8) = rb0;
        *(short8*)(Bs + s1 * 8) = rb1;
        __syncthreads();
        if (k0 + 32 < K) {           // prefetch next tile; flies under compute
            ra0 = *(const short8*)(a0p + k0 + 32);
            ra1 = *(const short8*)(a1p + k0 + 32);
            rb0 = *(const short8*)(b0p + k0 + 32);
            rb1 = *(const short8*)(b1p + k0 + 32);
        }
        short8 af[4], bfr[4];
        #pragma unroll
        for (int m = 0; m < 4; ++m)
            af[m] = *(const short8*)(As + (wr + m * 16 + (l & 15)) * 32 + (l >> 4) * 8);
        #pragma unroll
        for (int n = 0; n < 4; ++n)
            bfr[n] = *(const short8*)(Bs + (wc + n * 16 + (l & 15)) * 32 + (l >> 4) * 8);
        #pragma unroll
        for (int m = 0; m < 4; ++m)
            #pragma unroll
            for (int n = 0; n < 4; ++n)
                acc[m][n] = __builtin_amdgcn_mfma_f32_16x16x32_bf16(af[m], bfr[n], acc[m][n], 0, 0, 0);
    }

    int cr = (l >> 4) * 4;
    int cc = l & 15;
    #pragma unroll
    for (int m = 0; m < 4; ++m) {
        #pragma unroll
        for (int n = 0; n < 4; ++n) {
            int col = col0 + wc + n * 16 + cc;
            float bv = bias[col];
            if (OBF == 2) {
                int r0 = row0 + wr + m * 16 + cr;   // multiple of 4; 900%4==0
                if (r0 < M) {
                    int bb = r0 / 900;
                    int q = r0 - bb * 900;
                    ushort4 u;
                    u.x = f2bf(acc[m][n][0] + bv);
                    u.y = f2bf(acc[m][n][1] + bv);
                    u.z = f2bf(acc[m][n][2] + bv);
                    u.w = f2bf(acc[m][n][3] + bv);
                    *reinterpret_cast<ushort4*>(Cb + ((size_t)(bb * 256 + col)) * LQP + q) = u;
                }
            } else {
                #pragma unroll
                for (int j = 0; j < 4; ++j) {
                    int r = row0 + wr + m * 16 + cr + j;
                    if (r < M) {
                        float v = acc[m][n][j] + bv;
                        if (RELU) v = fmaxf(v, 0.f);
                        if (OBF) Cb[(size_t)r * ldc + col] = f2bf(v);
                        else     Cf[(size_t)r * ldc + col] = v;
                    }
                }
            }
        }
    }
}

// -------------------- value GEMM: A fp32, pipelined staging -----------------
__global__ __launch_bounds__(256) void bgemm_vf(int M, int N, int K,
        const float* __restrict__ A,
        const unsigned short* __restrict__ BT,
        const float* __restrict__ bias,
        unsigned short* __restrict__ Cb, int ldc) {
    __shared__ __align__(16) unsigned short As[128 * 32];
    __shared__ __align__(16) unsigned short Bs[128 * 32];
    int t = threadIdx.x;
    int l = t & 63;
    int w = t >> 6;
    int row0 = blockIdx.x * 128, col0 = blockIdx.y * 128;
    int wr = (w >> 1) * 64, wc = (w & 1) * 64;
    f32x4 acc[4][4];
    #pragma unroll
    for (int m = 0; m < 4; ++m)
        #pragma unroll
        for (int n = 0; n < 4; ++n) acc[m][n] = (f32x4){0.f, 0.f, 0.f, 0.f};

    int s0 = t, s1 = t + 256;
    int r0c = min(row0 + (s0 >> 2), M - 1);     // clamp: src has no pad rows
    int r1c = min(row0 + (s1 >> 2), M - 1);
    const float* a0p = A + (size_t)r0c * K + (s0 & 3) * 8;
    const float* a1p = A + (size_t)r1c * K + (s1 & 3) * 8;
    const unsigned short* Bg = BT + (size_t)col0 * K;
    const unsigned short* b0p = Bg + (size_t)(s0 >> 2) * K + (s0 & 3) * 8;
    const unsigned short* b1p = Bg + (size_t)(s1 >> 2) * K + (s1 & 3) * 8;

    // prologue prefetch (fp32 A kept raw in regs; convert at write)
    float4 fa0 = *(const float4*)(a0p);
    float4 fa1 = *(const float4*)(a0p + 4);
    float4 fb0 = *(const float4*)(a1p);
    float4 fb1 = *(const float4*)(a1p + 4);
    short8 rb0 = *(const short8*)(b0p);
    short8 rb1 = *(const short8*)(b1p);

    for (int k0 = 0; k0 < K; k0 += 32) {
        short8 ra0, ra1;
        ra0[0] = (short)f2bf(fa0.x); ra0[1] = (short)f2bf(fa0.y);
        ra0[2] = (short)f2bf(fa0.z); ra0[3] = (short)f2bf(fa0.w);
        ra0[4] = (short)f2bf(fa1.x); ra0[5] = (short)f2bf(fa1.y);
        ra0[6] = (short)f2bf(fa1.z); ra0[7] = (short)f2bf(fa1.w);
        ra1[0] = (short)f2bf(fb0.x); ra1[1] = (short)f2bf(fb0.y);
        ra1[2] = (short)f2bf(fb0.z); ra1[3] = (short)f2bf(fb0.w);
        ra1[4] = (short)f2bf(fb1.x); ra1[5] = (short)f2bf(fb1.y);
        ra1[6] = (short)f2bf(fb1.z); ra1[7] = (short)f2bf(fb1.w);
        __syncthreads();
        *(short8*)(As + s0 * 8) = ra0;
        *(short8*)(As + s1 * 8) = ra1;
        *(short8*)(Bs + s0 * 8) = rb0;
        *(short8*)(Bs + s1 * 8) = rb1;
        __syncthreads();
        if (k0 + 32 < K) {
            fa0 = *(const float4*)(a0p + k0 + 32);
            fa1 = *(const float4*)(a0p + k0 + 36);
            fb0 = *(const float4*)(a1p + k0 + 32);
            fb1 = *(const float4*)(a1p + k0 + 36);
            rb0 = *(const short8*)(b0p + k0 + 32);
            rb1 = *(const short8*)(b1p + k0 + 32);
        }
        short8 af[4], bfr[4];
        #pragma unroll
        for (int m = 0; m < 4; ++m)
            af[m] = *(const short8*)(As + (wr + m * 16 + (l & 15)) * 32 + (l >> 4) * 8);
        #pragma unroll
        for (int n = 0; n < 4; ++n)
            bfr[n] = *(const short8*)(Bs + (wc + n * 16 + (l & 15)) * 32 + (l >> 4) * 8);
        #pragma unroll
        for (int m = 0; m < 4; ++m)
            #pragma unroll
            for (int n = 0; n < 4; ++n)
                acc[m][n] = __builtin_amdgcn_mfma_f32_16x16x32_bf16(af[m], bfr[n], acc[m][n], 0, 0, 0);
    }

    int cr = (l >> 4) * 4;
    int cc = l & 15;
    #pragma unroll
    for (int m = 0; m < 4; ++m) {
        #pragma unroll
        for (int n = 0; n < 4; ++n) {
            int col = col0 + wc + n * 16 + cc;
            float bv = bias[col];
            #pragma unroll
            for (int j = 0; j < 4; ++j) {
                int r = row0 + wr + m * 16 + cr + j;
                if (r < M)
                    Cb[(size_t)r * ldc + col] = f2bf(acc[m][n][j] + bv);
            }
        }
    }
}

// -------------------- MFMA flash self-attention ------------------------------
__global__ __launch_bounds__(256) void flash_mfma(const unsigned short* __restrict__ qk,
                                                  const unsigned short* __restrict__ vt,
                                                  unsigned short* __restrict__ out) {
    __shared__ unsigned short P_lds[4][16][72];
    int t = threadIdx.x;
    int l = t & 63, w = t >> 6;
    int lr = l & 15, lg = l >> 4;
    int qt = blockIdx.x, h = blockIdx.y, b = blockIdx.z;
    const float scale = 0.17677669529663687f;

    short8 qf = *(const short8*)(qk + (size_t)(b * LQm + qt * 64 + w * 16 + lr) * 512 + h * 32 + lg * 8);

    f32x4 accO[2];
    accO[0] = (f32x4){0.f, 0.f, 0.f, 0.f};
    accO[1] = (f32x4){0.f, 0.f, 0.f, 0.f};
    float mrow[4] = {-1e30f, -1e30f, -1e30f, -1e30f};
    float lrow[4] = {0.f, 0.f, 0.f, 0.f};
    const f32x4 zero = (f32x4){0.f, 0.f, 0.f, 0.f};
    const unsigned short* vtb = vt + ((size_t)(b * 256 + h * 32)) * LQP;

    for (int kt = 0; kt < 15; ++kt) {
        int k0 = kt * 64;
        f32x4 sfr[4];
        #pragma unroll
        for (int ks = 0; ks < 4; ++ks) {
            short8 kf = *(const short8*)(qk + (size_t)(b * LQm + k0 + ks * 16 + lr) * 512 + 256 + h * 32 + lg * 8);
            sfr[ks] = __builtin_amdgcn_mfma_f32_16x16x32_bf16(qf, kf, zero, 0, 0, 0);
        }
        float sv[4][4];
        #pragma unroll
        for (int ks = 0; ks < 4; ++ks) {
            bool valid = (k0 + ks * 16 + lr) < LQm;
            #pragma unroll
            for (int j = 0; j < 4; ++j)
                sv[ks][j] = valid ? sfr[ks][j] * scale : -1e30f;
        }
        float tm[4], newm[4], rr[4], ps[4];
        #pragma unroll
        for (int j = 0; j < 4; ++j)
            tm[j] = fmaxf(fmaxf(sv[0][j], sv[1][j]), fmaxf(sv[2][j], sv[3][j]));
        #pragma unroll
        for (int msk = 1; msk <= 8; msk <<= 1) {
            #pragma unroll
            for (int j = 0; j < 4; ++j) tm[j] = fmaxf(tm[j], __shfl_xor(tm[j], msk));
        }
        #pragma unroll
        for (int j = 0; j < 4; ++j) {
            newm[j] = fmaxf(mrow[j], tm[j]);
            rr[j] = __expf(mrow[j] - newm[j]);
            mrow[j] = newm[j];
            ps[j] = 0.f;
        }
        float pv[4][4];
        #pragma unroll
        for (int ks = 0; ks < 4; ++ks)
            #pragma unroll
            for (int j = 0; j < 4; ++j) {
                pv[ks][j] = __expf(sv[ks][j] - newm[j]);
                ps[j] += pv[ks][j];
            }
        #pragma unroll
        for (int msk = 1; msk <= 8; msk <<= 1) {
            #pragma unroll
            for (int j = 0; j < 4; ++j) ps[j] += __shfl_xor(ps[j], msk);
        }
        #pragma unroll
        for (int j = 0; j < 4; ++j) lrow[j] = lrow[j] * rr[j] + ps[j];
        #pragma unroll
        for (int n = 0; n < 2; ++n)
            #pragma unroll
            for (int j = 0; j < 4; ++j) accO[n][j] *= rr[j];
        #pragma unroll
        for (int ks = 0; ks < 4; ++ks)
            #pragma unroll
            for (int j = 0; j < 4; ++j)
                P_lds[w][lg * 4 + j][ks * 16 + lr] = f2bf(pv[ks][j]);
        #pragma unroll
        for (int kh2 = 0; kh2 < 2; ++kh2) {
            short8 pf = *(const short8*)(&P_lds[w][lr][kh2 * 32 + lg * 8]);
            #pragma unroll
            for (int n = 0; n < 2; ++n) {
                short8 vf = *(const short8*)(vtb + (size_t)(n * 16 + lr) * LQP + k0 + kh2 * 32 + lg * 8);
                accO[n] = __builtin_amdgcn_mfma_f32_16x16x32_bf16(pf, vf, accO[n], 0, 0, 0);
            }
        }
    }
    float inv[4];
    #pragma unroll
    for (int j = 0; j < 4; ++j) inv[j] = 1.0f / lrow[j];
    #pragma unroll
    for (int n = 0; n < 2; ++n)
        #pragma unroll
        for (int j = 0; j < 4; ++j) {
            int q = qt * 64 + w * 16 + lg * 4 + j;
            if (q < LQm)
                out[(size_t)(b * LQm + q) * 256 + h * 32 + n * 16 + lr] = f2bf(accO[n][j] * inv[j]);
        }
}

// -------------------- fused residual add + LayerNorm (wave per row) ---------
template <int DUAL, int QP>
__global__ __launch_bounds__(256) void add_ln_kernel(const float* __restrict__ x,
                                                     const float* __restrict__ r,
                                                     const float* __restrict__ w,
                                                     const float* __restrict__ b,
                                                     const float* __restrict__ qpos,
                                                     float* __restrict__ out,
                                                     unsigned short* __restrict__ outb,
                                                     unsigned short* __restrict__ outq) {
    int row = blockIdx.x * 4 + (threadIdx.x >> 6);
    int lane = threadIdx.x & 63;
    size_t i4 = (size_t)row * 64 + lane;
    float4 xv = reinterpret_cast<const float4*>(x)[i4];
    float4 rv = reinterpret_cast<const float4*>(r)[i4];
    float4 v = make_float4(xv.x + rv.x, xv.y + rv.y, xv.z + rv.z, xv.w + rv.w);
    float s = v.x + v.y + v.z + v.w;
    #pragma unroll
    for (int msk = 1; msk <= 32; msk <<= 1) s += __shfl_xor(s, msk);
    float mean = s * (1.0f / Dm);
    float4 dv = make_float4(v.x - mean, v.y - mean, v.z - mean, v.w - mean);
    float sq = dv.x * dv.x + dv.y * dv.y + dv.z * dv.z + dv.w * dv.w;
    #pragma unroll
    for (int msk = 1; msk <= 32; msk <<= 1) sq += __shfl_xor(sq, msk);
    float is = rsqrtf(sq * (1.0f / Dm) + 1e-5f);
    float4 wv = reinterpret_cast<const float4*>(w)[lane];
    float4 bv = reinterpret_cast<const float4*>(b)[lane];
    float4 res = make_float4(dv.x * is * wv.x + bv.x, dv.y * is * wv.y + bv.y,
                             dv.z * is * wv.z + bv.z, dv.w * is * wv.w + bv.w);
    reinterpret_cast<float4*>(out)[i4] = res;
    if (DUAL) {
        ushort4 u;
        u.x = f2bf(res.x); u.y = f2bf(res.y); u.z = f2bf(res.z); u.w = f2bf(res.w);
        reinterpret_cast<ushort4*>(outb)[i4] = u;
    }
    if (QP) {
        float4 qv = reinterpret_cast<const float4*>(qpos)[i4];
        ushort4 u;
        u.x = f2bf(res.x + qv.x); u.y = f2bf(res.y + qv.y);
        u.z = f2bf(res.z + qv.z); u.w = f2bf(res.w + qv.w);
        reinterpret_cast<ushort4*>(outq)[i4] = u;
    }
}

// -------------------- ms-deformable sampling: wave per query ----------------
__global__ __launch_bounds__(256) void msdeform_kernel(const unsigned short* __restrict__ value,
                                                       const float* __restrict__ ref,
                                                       const float* __restrict__ off,
                                                       const float* __restrict__ awl,
                                                       unsigned short* __restrict__ out) {
    const int HL[4] = {100, 50, 25, 13};
    const int ST[4] = {0, 10000, 12500, 13125};
    __shared__ float lsx[4][128], lsy[4][128], wtab[4][128];
    __shared__ float2 ctab[4][512];
    int wv = threadIdx.x >> 6, lane = threadIdx.x & 63;
    int m = blockIdx.x * 4 + wv;
    int b = m / LQm;

    #pragma unroll
    for (int e = lane; e < 128; e += 64) {
        int lev = (e >> 2) & 3;
        float rx = ref[((size_t)m * NLEVm + lev) * 2 + 0];
        float ry = ref[((size_t)m * NLEVm + lev) * 2 + 1];
        float ox = off[(size_t)m * 256 + e * 2 + 0];
        float oy = off[(size_t)m * 256 + e * 2 + 1];
        float Wf = (float)HL[lev];
        lsx[wv][e] = (rx + ox / Wf) * Wf - 0.5f;
        lsy[wv][e] = (ry + oy / Wf) * Wf - 0.5f;
        wtab[wv][e] = awl[(size_t)m * 128 + e];
    }
    __syncthreads();
    if (lane < NHm) {
        int h = lane;
        float mx = -1e30f;
        #pragma unroll
        for (int i = 0; i < 16; i++) mx = fmaxf(mx, wtab[wv][h * 16 + i]);
        float s = 0.f;
        #pragma unroll
        for (int i = 0; i < 16; i++) {
            float e = __expf(wtab[wv][h * 16 + i] - mx);
            wtab[wv][h * 16 + i] = e; s += e;
        }
        float inv = 1.0f / s;
        #pragma unroll
        for (int i = 0; i < 16; i++) wtab[wv][h * 16 + i] *= inv;
    }
    __syncthreads();
    #pragma unroll
    for (int j = 0; j < 8; ++j) {
        int e2 = lane * 8 + j;
        int c = e2 & 3, e = e2 >> 2;
        int lev = (e >> 2) & 3;
        int Wl = HL[lev];
        float lx = lsx[wv][e], ly = lsy[wv][e];
        float x0f = floorf(lx), y0f = floorf(ly);
        float fx = lx - x0f, fy = ly - y0f;
        int dx = c & 1, dy = c >> 1;
        int xi = (int)x0f + dx, yi = (int)y0f + dy;
        bool valid = (xi >= 0) && (xi < Wl) && (yi >= 0) && (yi < Wl);
        float wc = valid ? ((dx ? fx : 1.0f - fx) * (dy ? fy : 1.0f - fy)) * wtab[wv][e] : 0.f;
        int xc = min(max(xi, 0), Wl - 1), yc = min(max(yi, 0), Wl - 1);
        int row = b * LENm + ST[lev] + yc * Wl + xc;
        ctab[wv][e2] = make_float2(__int_as_float(row), wc);
    }
    __syncthreads();
    int h = lane >> 3, dg = lane & 7;
    const unsigned short* basep = value + h * 32 + dg * 4;
    float a0 = 0.f, a1 = 0.f, a2 = 0.f, a3 = 0.f;
    #pragma unroll
    for (int i = 0; i < 16; ++i) {
        #pragma unroll
        for (int c = 0; c < 4; ++c) {
            float2 cc = ctab[wv][(h * 16 + i) * 4 + c];
            int row = __float_as_int(cc.x);
            float wc = cc.y;
            ushort4 v = *reinterpret_cast<const ushort4*>(basep + (size_t)row * 256);
            a0 += wc * bf2f(v.x); a1 += wc * bf2f(v.y);
            a2 += wc * bf2f(v.z); a3 += wc * bf2f(v.w);
        }
    }
    ushort4 o;
    o.x = f2bf(a0); o.y = f2bf(a1); o.z = f2bf(a2); o.w = f2bf(a3);
    *reinterpret_cast<ushort4*>(out + (size_t)m * 256 + h * 32 + dg * 4) = o;
}

// ------------------------------------------------------------------
extern "C" void kernel_launch(void* const* d_in, const int* in_sizes, int n_in,
                              void* d_out, int out_size, void* d_ws, size_t ws_size,
                              hipStream_t stream) {
    const float* tgt   = (const float*)d_in[0];
    const float* qpos  = (const float*)d_in[1];
    const float* refp  = (const float*)d_in[2];
    const float* src   = (const float*)d_in[3];
    const float* qkv_w = (const float*)d_in[6];
    const float* qkv_b = (const float*)d_in[7];
    const float* out_w = (const float*)d_in[8];
    const float* out_b = (const float*)d_in[9];
    const float* ln2_w = (const float*)d_in[10];
    const float* ln2_b = (const float*)d_in[11];
    const float* val_w = (const float*)d_in[12];
    const float* val_b = (const float*)d_in[13];
    const float* off_w = (const float*)d_in[14];
    const float* off_b = (const float*)d_in[15];
    const float* aw_w  = (const float*)d_in[16];
    const float* aw_b  = (const float*)d_in[17];
    const float* op_w  = (const float*)d_in[18];
    const float* op_b  = (const float*)d_in[19];
    const float* ln1_w = (const float*)d_in[20];
    const float* ln1_b = (const float*)d_in[21];
    const float* w1    = (const float*)d_in[22];
    const float* b1    = (const float*)d_in[23];
    const float* w2    = (const float*)d_in[24];
    const float* b2    = (const float*)d_in[25];
    const float* ln3_w = (const float*)d_in[26];
    const float* ln3_b = (const float*)d_in[27];

    char* base = (char*)d_ws;
    unsigned short* value_bf  = (unsigned short*)(base);                      // 54,460,416
    unsigned short* hidden_bf = (unsigned short*)(base + 54460416);           // MQP*1024*2
    unsigned short* t2_bf     = (unsigned short*)(base + 54460416 + 14942208);
    unsigned short* qk_bf = (unsigned short*)(base + 108920832);              // MQP*512*2
    float* offb = (float*)(base + 108920832);                                 // aliases qk_bf (after flash)
    float* awb  = (float*)(base + 108920832 + 7372800);
    unsigned short* Vt = (unsigned short*)(base + 123666432);                 // 8*256*960*2
    float* S1   = (float*)(base + 123666432);                                 // aliases Vt (after flash)
    float* t1   = (float*)(base + 131039232);
    float* t2   = (float*)(base + 138412032);
    unsigned short* Qbf     = (unsigned short*)(base + 145784832);
    unsigned short* tgt_bf  = (unsigned short*)(base + 149520384);
    unsigned short* attn_bf = (unsigned short*)(base + 153255936);
    unsigned short* ca_bf   = (unsigned short*)(base + 156991488);
    unsigned short* BT_qkv  = (unsigned short*)(base + 160727040);            // [768][256]
    unsigned short* BT_out  = BT_qkv + 768 * 256;
    unsigned short* BT_val  = BT_out + 256 * 256;
    unsigned short* BT_off  = BT_val + 256 * 256;
    unsigned short* BT_aw   = BT_off + 256 * 256;
    unsigned short* BT_op   = BT_aw + 128 * 256;
    unsigned short* BT_w1   = BT_op + 256 * 256;
    unsigned short* BT_w2   = BT_w1 + 1024 * 256;
    float* outp = (float*)d_out;

    dim3 blk(256);
    wt_tiled<<<dim3(12, 4), blk, 0, stream>>>(qkv_w, BT_qkv, 768, 256);
    wt_tiled<<<dim3(4, 4),  blk, 0, stream>>>(out_w, BT_out, 256, 256);
    wt_tiled<<<dim3(4, 4),  blk, 0, stream>>>(val_w, BT_val, 256, 256);
    wt_tiled<<<dim3(4, 4),  blk, 0, stream>>>(off_w, BT_off, 256, 256);
    wt_tiled<<<dim3(2, 4),  blk, 0, stream>>>(aw_w,  BT_aw,  128, 256);
    wt_tiled<<<dim3(4, 4),  blk, 0, stream>>>(op_w,  BT_op,  256, 256);
    wt_tiled<<<dim3(16, 4), blk, 0, stream>>>(w1,    BT_w1, 1024, 256);
    wt_tiled<<<dim3(4, 16), blk, 0, stream>>>(w2,    BT_w2,  256, 1024);

    prep0<<<dim3(1824), blk, 0, stream>>>(tgt, qpos, tgt_bf, Qbf, MQ * Dm / 4, MQP * Dm / 4);

    bgemm<0, 1><<<dim3(57, 4), blk, 0, stream>>>(MQ, 512, 256, Qbf, BT_qkv, qkv_b, nullptr, qk_bf, 512);
    bgemm<0, 2><<<dim3(57, 2), blk, 0, stream>>>(MQ, 256, 256, tgt_bf, BT_qkv + 512 * 256, qkv_b + 512, nullptr, Vt, 256);
    vtpad_kernel<<<dim3(480), blk, 0, stream>>>(Vt);
    flash_mfma<<<dim3(15, NHm, Bm), blk, 0, stream>>>(qk_bf, Vt, attn_bf);
    bgemm<0, 0><<<dim3(57, 2), blk, 0, stream>>>(MQ, 256, 256, attn_bf, BT_out, out_b, S1, nullptr, 256);
    add_ln_kernel<0, 1><<<dim3(1800), blk, 0, stream>>>(tgt, S1, ln2_w, ln2_b, qpos, t1, nullptr, Qbf);
    bgemm_vf<<<dim3(831, 2), blk, 0, stream>>>(MV, 256, 256, src, BT_val, val_b, value_bf, 256);
    bgemm<0, 0><<<dim3(57, 2), blk, 0, stream>>>(MQ, 256, 256, Qbf, BT_off, off_b, offb, nullptr, 256);
    bgemm<0, 0><<<dim3(57, 1), blk, 0, stream>>>(MQ, 128, 256, Qbf, BT_aw, aw_b, awb, nullptr, 128);
    msdeform_kernel<<<dim3(1800), blk, 0, stream>>>(value_bf, refp, offb, awb, ca_bf);
    bgemm<0, 0><<<dim3(57, 2), blk, 0, stream>>>(MQ, 256, 256, ca_bf, BT_op, op_b, S1, nullptr, 256);
    add_ln_kernel<1, 0><<<dim3(1800), blk, 0, stream>>>(t1, S1, ln1_w, ln1_b, nullptr, t2, t2_bf, nullptr);
    bgemm<1, 1><<<dim3(57, 8), blk, 0, stream>>>(MQ, DFFNm, 256, t2_bf, BT_w1, b1, nullptr, hidden_bf, DFFNm);
    bgemm<0, 0><<<dim3(57, 2), blk, 0, stream>>>(MQ, 256, 1024, hidden_bf, BT_w2, b2, S1, nullptr, 256);
    add_ln_kernel<0, 0><<<dim3(1800), blk, 0, stream>>>(t2, S1, ln3_w, ln3_b, nullptr, outp, nullptr, nullptr);
}

// Round 8
// 281.540 us; speedup vs baseline: 6.2122x; 1.0336x over previous
//
#include <hip/hip_runtime.h>
#include <math.h>

#define Dm    256
#define NHm   8
#define DHm   32
#define NLEVm 4
#define NPTSm 4
#define DFFNm 1024
#define Bm    8
#define LQm   900
#define LENm  13294
#define MQ    (Bm * LQm)      // 7200
#define MV    (Bm * LENm)     // 106352
#define MQP   7296            // MQ padded to 128
#define MVP   106368          // MV padded to 128
#define LQP   960             // keys padded to 15*64

typedef __attribute__((ext_vector_type(8))) short short8;   // 8 bf16 (4 VGPRs)
typedef __attribute__((ext_vector_type(4))) float f32x4;    // MFMA acc

__device__ __forceinline__ unsigned short f2bf(float f) {
    unsigned int b = __float_as_uint(f);
    unsigned int r = (b + 0x7FFFu + ((b >> 16) & 1u)) >> 16;
    return (unsigned short)r;
}
__device__ __forceinline__ float bf2f(unsigned short u) {
    return __uint_as_float(((unsigned int)u) << 16);
}

// -------------------- prep: tgt_bf = bf16(tgt); Qbf = bf16(tgt+qpos) --------
__global__ __launch_bounds__(256) void prep0(const float* __restrict__ tgt,
                                             const float* __restrict__ qpos,
                                             unsigned short* __restrict__ tgtb,
                                             unsigned short* __restrict__ qb,
                                             int n4, int n4pad) {
    int i = blockIdx.x * blockDim.x + threadIdx.x;
    int stride = gridDim.x * blockDim.x;
    for (; i < n4pad; i += stride) {
        ushort4 ut, uq;
        if (i < n4) {
            float4 x = reinterpret_cast<const float4*>(tgt)[i];
            float4 y = reinterpret_cast<const float4*>(qpos)[i];
            ut.x = f2bf(x.x); ut.y = f2bf(x.y); ut.z = f2bf(x.z); ut.w = f2bf(x.w);
            uq.x = f2bf(x.x + y.x); uq.y = f2bf(x.y + y.y);
            uq.z = f2bf(x.z + y.z); uq.w = f2bf(x.w + y.w);
        } else {
            ut.x = ut.y = ut.z = ut.w = 0;
            uq.x = uq.y = uq.z = uq.w = 0;
        }
        reinterpret_cast<ushort4*>(tgtb)[i] = ut;
        reinterpret_cast<ushort4*>(qb)[i] = uq;
    }
}

// -------------------- zero Vt pad key-columns [900,960) --------------------
__global__ __launch_bounds__(256) void vtpad_kernel(unsigned short* __restrict__ vt) {
    int i = blockIdx.x * 256 + threadIdx.x;       // 2048*60 = 122880
    int row = i / 60, c = 900 + (i % 60);
    vt[(size_t)row * LQP + c] = 0;
}

// -------------------- tiled weight transpose: BT[n][k] = bf16(W[k][n]) ------
__global__ __launch_bounds__(256) void wt_tiled(const float* __restrict__ W,
                                                unsigned short* __restrict__ BT,
                                                int N, int K) {
    __shared__ float tile[64][65];
    int n0 = blockIdx.x * 64, k0 = blockIdx.y * 64;
    int t = threadIdx.x;
    #pragma unroll
    for (int r0 = 0; r0 < 64; r0 += 16) {
        int r = r0 + (t >> 4);
        int c = (t & 15) * 4;
        float4 v = *reinterpret_cast<const float4*>(W + (size_t)(k0 + r) * N + n0 + c);
        tile[r][c + 0] = v.x; tile[r][c + 1] = v.y; tile[r][c + 2] = v.z; tile[r][c + 3] = v.w;
    }
    __syncthreads();
    #pragma unroll
    for (int s = t; s < 512; s += 256) {
        int r = s >> 3, c8 = (s & 7) * 8;
        short8 u;
        #pragma unroll
        for (int j = 0; j < 8; ++j) u[j] = (short)f2bf(tile[c8 + j][r]);
        *reinterpret_cast<short8*>(BT + (size_t)(n0 + r) * K + k0 + c8) = u;
    }
}

// -------------------- bf16 MFMA GEMM (double-buffered LDS, 1 barrier/iter) --
// OBF: 0 fp32 out, 1 bf16 out, 2 Vt out, 3 split (Cf ldc=256 / Cf2 ldc=128 at col 256)
template <int RELU, int OBF>
__global__ __launch_bounds__(256) void bgemm(int M, int N, int K,
        const unsigned short* __restrict__ A,
        const unsigned short* __restrict__ BT,
        const float* __restrict__ bias, const float* __restrict__ bias2,
        float* __restrict__ Cf, float* __restrict__ Cf2,
        unsigned short* __restrict__ Cb, int ldc) {
    __shared__ __align__(16) unsigned short As[2][128 * 32];
    __shared__ __align__(16) unsigned short Bs[2][128 * 32];
    int t = threadIdx.x;
    int l = t & 63;
    int w = t >> 6;
    int row0 = blockIdx.x * 128, col0 = blockIdx.y * 128;
    int wr = (w >> 1) * 64, wc = (w & 1) * 64;
    f32x4 acc[4][4];
    #pragma unroll
    for (int m = 0; m < 4; ++m)
        #pragma unroll
        for (int n = 0; n < 4; ++n) acc[m][n] = (f32x4){0.f, 0.f, 0.f, 0.f};

    int s0 = t, s1 = t + 256;
    const unsigned short* Ag = A + (size_t)row0 * K;
    const unsigned short* Bg = BT + (size_t)col0 * K;
    const unsigned short* a0p = Ag + (size_t)(s0 >> 2) * K + (s0 & 3) * 8;
    const unsigned short* a1p = Ag + (size_t)(s1 >> 2) * K + (s1 & 3) * 8;
    const unsigned short* b0p = Bg + (size_t)(s0 >> 2) * K + (s0 & 3) * 8;
    const unsigned short* b1p = Bg + (size_t)(s1 >> 2) * K + (s1 & 3) * 8;

    short8 ra0 = *(const short8*)(a0p);
    short8 ra1 = *(const short8*)(a1p);
    short8 rb0 = *(const short8*)(b0p);
    short8 rb1 = *(const short8*)(b1p);

    int cur = 0;
    for (int k0 = 0; k0 < K; k0 += 32) {
        unsigned short* Ac = As[cur];
        unsigned short* Bc = Bs[cur];
        *(short8*)(Ac + s0 * 8) = ra0;
        *(short8*)(Ac + s1 * 8) = ra1;
        *(short8*)(Bc + s0 * 8) = rb0;
        *(short8*)(Bc + s1 * 8) = rb1;
        if (k0 + 32 < K) {       // issue next tile; lands during compute+barrier
            ra0 = *(const short8*)(a0p + k0 + 32);
            ra1 = *(const short8*)(a1p + k0 + 32);
            rb0 = *(const short8*)(b0p + k0 + 32);
            rb1 = *(const short8*)(b1p + k0 + 32);
        }
        __syncthreads();
        short8 af[4], bfr[4];
        #pragma unroll
        for (int m = 0; m < 4; ++m)
            af[m] = *(const short8*)(Ac + (wr + m * 16 + (l & 15)) * 32 + (l >> 4) * 8);
        #pragma unroll
        for (int n = 0; n < 4; ++n)
            bfr[n] = *(const short8*)(Bc + (wc + n * 16 + (l & 15)) * 32 + (l >> 4) * 8);
        #pragma unroll
        for (int m = 0; m < 4; ++m)
            #pragma unroll
            for (int n = 0; n < 4; ++n)
                acc[m][n] = __builtin_amdgcn_mfma_f32_16x16x32_bf16(af[m], bfr[n], acc[m][n], 0, 0, 0);
        cur ^= 1;
    }

    int cr = (l >> 4) * 4;
    int cc = l & 15;
    #pragma unroll
    for (int m = 0; m < 4; ++m) {
        #pragma unroll
        for (int n = 0; n < 4; ++n) {
            int col = col0 + wc + n * 16 + cc;
            if (OBF == 2) {
                float bv = bias[col];
                int r0 = row0 + wr + m * 16 + cr;   // multiple of 4; 900%4==0
                if (r0 < M) {
                    int bb = r0 / 900;
                    int q = r0 - bb * 900;
                    ushort4 u;
                    u.x = f2bf(acc[m][n][0] + bv);
                    u.y = f2bf(acc[m][n][1] + bv);
                    u.z = f2bf(acc[m][n][2] + bv);
                    u.w = f2bf(acc[m][n][3] + bv);
                    *reinterpret_cast<ushort4*>(Cb + ((size_t)(bb * 256 + col)) * LQP + q) = u;
                }
            } else if (OBF == 3) {
                float bv = (col < 256) ? bias[col] : bias2[col - 256];
                #pragma unroll
                for (int j = 0; j < 4; ++j) {
                    int r = row0 + wr + m * 16 + cr + j;
                    if (r < M) {
                        float v = acc[m][n][j] + bv;
                        if (col < 256) Cf[(size_t)r * 256 + col] = v;
                        else           Cf2[(size_t)r * 128 + (col - 256)] = v;
                    }
                }
            } else {
                float bv = bias[col];
                #pragma unroll
                for (int j = 0; j < 4; ++j) {
                    int r = row0 + wr + m * 16 + cr + j;
                    if (r < M) {
                        float v = acc[m][n][j] + bv;
                        if (RELU) v = fmaxf(v, 0.f);
                        if (OBF) Cb[(size_t)r * ldc + col] = f2bf(v);
                        else     Cf[(size_t)r * ldc + col] = v;
                    }
                }
            }
        }
    }
}

// -------------------- value GEMM: A fp32, double-buffered staging -----------
__global__ __launch_bounds__(256) void bgemm_vf(int M, int N, int K,
        const float* __restrict__ A,
        const unsigned short* __restrict__ BT,
        const float* __restrict__ bias,
        unsigned short* __restrict__ Cb, int ldc) {
    __shared__ __align__(16) unsigned short As[2][128 * 32];
    __shared__ __align__(16) unsigned short Bs[2][128 * 32];
    int t = threadIdx.x;
    int l = t & 63;
    int w = t >> 6;
    int row0 = blockIdx.x * 128, col0 = blockIdx.y * 128;
    int wr = (w >> 1) * 64, wc = (w & 1) * 64;
    f32x4 acc[4][4];
    #pragma unroll
    for (int m = 0; m < 4; ++m)
        #pragma unroll
        for (int n = 0; n < 4; ++n) acc[m][n] = (f32x4){0.f, 0.f, 0.f, 0.f};

    int s0 = t, s1 = t + 256;
    int r0c = min(row0 + (s0 >> 2), M - 1);     // clamp: src has no pad rows
    int r1c = min(row0 + (s1 >> 2), M - 1);
    const float* a0p = A + (size_t)r0c * K + (s0 & 3) * 8;
    const float* a1p = A + (size_t)r1c * K + (s1 & 3) * 8;
    const unsigned short* Bg = BT + (size_t)col0 * K;
    const unsigned short* b0p = Bg + (size_t)(s0 >> 2) * K + (s0 & 3) * 8;
    const unsigned short* b1p = Bg + (size_t)(s1 >> 2) * K + (s1 & 3) * 8;

    float4 fa0 = *(const float4*)(a0p);
    float4 fa1 = *(const float4*)(a0p + 4);
    float4 fb0 = *(const float4*)(a1p);
    float4 fb1 = *(const float4*)(a1p + 4);
    short8 rb0 = *(const short8*)(b0p);
    short8 rb1 = *(const short8*)(b1p);

    int cur = 0;
    for (int k0 = 0; k0 < K; k0 += 32) {
        unsigned short* Ac = As[cur];
        unsigned short* Bc = Bs[cur];
        short8 ra0, ra1;
        ra0[0] = (short)f2bf(fa0.x); ra0[1] = (short)f2bf(fa0.y);
        ra0[2] = (short)f2bf(fa0.z); ra0[3] = (short)f2bf(fa0.w);
        ra0[4] = (short)f2bf(fa1.x); ra0[5] = (short)f2bf(fa1.y);
        ra0[6] = (short)f2bf(fa1.z); ra0[7] = (short)f2bf(fa1.w);
        ra1[0] = (short)f2bf(fb0.x); ra1[1] = (short)f2bf(fb0.y);
        ra1[2] = (short)f2bf(fb0.z); ra1[3] = (short)f2bf(fb0.w);
        ra1[4] = (short)f2bf(fb1.x); ra1[5] = (short)f2bf(fb1.y);
        ra1[6] = (short)f2bf(fb1.z); ra1[7] = (short)f2bf(fb1.w);
        *(short8*)(Ac + s0 * 8) = ra0;
        *(short8*)(Ac + s1 * 8) = ra1;
        *(short8*)(Bc + s0 * 8) = rb0;
        *(short8*)(Bc + s1 * 8) = rb1;
        if (k0 + 32 < K) {
            fa0 = *(const float4*)(a0p + k0 + 32);
            fa1 = *(const float4*)(a0p + k0 + 36);
            fb0 = *(const float4*)(a1p + k0 + 32);
            fb1 = *(const float4*)(a1p + k0 + 36);
            rb0 = *(const short8*)(b0p + k0 + 32);
            rb1 = *(const short8*)(b1p + k0 + 32);
        }
        __syncthreads();
        short8 af[4], bfr[4];
        #pragma unroll
        for (int m = 0; m < 4; ++m)
            af[m] = *(const short8*)(Ac + (wr + m * 16 + (l & 15)) * 32 + (l >> 4) * 8);
        #pragma unroll
        for (int n = 0; n < 4; ++n)
            bfr[n] = *(const short8*)(Bc + (wc + n * 16 + (l & 15)) * 32 + (l >> 4) * 8);
        #pragma unroll
        for (int m = 0; m < 4; ++m)
            #pragma unroll
            for (int n = 0; n < 4; ++n)
                acc[m][n] = __builtin_amdgcn_mfma_f32_16x16x32_bf16(af[m], bfr[n], acc[m][n], 0, 0, 0);
        cur ^= 1;
    }

    int cr = (l >> 4) * 4;
    int cc = l & 15;
    #pragma unroll
    for (int m = 0; m < 4; ++m) {
        #pragma unroll
        for (int n = 0; n < 4; ++n) {
            int col = col0 + wc + n * 16 + cc;
            float bv = bias[col];
            #pragma unroll
            for (int j = 0; j < 4; ++j) {
                int r = row0 + wr + m * 16 + cr + j;
                if (r < M)
                    Cb[(size_t)r * ldc + col] = f2bf(acc[m][n][j] + bv);
            }
        }
    }
}

// -------------------- MFMA flash self-attention ------------------------------
__global__ __launch_bounds__(256) void flash_mfma(const unsigned short* __restrict__ qk,
                                                  const unsigned short* __restrict__ vt,
                                                  unsigned short* __restrict__ out) {
    __shared__ unsigned short P_lds[4][16][72];
    int t = threadIdx.x;
    int l = t & 63, w = t >> 6;
    int lr = l & 15, lg = l >> 4;
    int qt = blockIdx.x, h = blockIdx.y, b = blockIdx.z;
    const float scale = 0.17677669529663687f;

    short8 qf = *(const short8*)(qk + (size_t)(b * LQm + qt * 64 + w * 16 + lr) * 512 + h * 32 + lg * 8);

    f32x4 accO[2];
    accO[0] = (f32x4){0.f, 0.f, 0.f, 0.f};
    accO[1] = (f32x4){0.f, 0.f, 0.f, 0.f};
    float mrow[4] = {-1e30f, -1e30f, -1e30f, -1e30f};
    float lrow[4] = {0.f, 0.f, 0.f, 0.f};
    const f32x4 zero = (f32x4){0.f, 0.f, 0.f, 0.f};
    const unsigned short* vtb = vt + ((size_t)(b * 256 + h * 32)) * LQP;

    for (int kt = 0; kt < 15; ++kt) {
        int k0 = kt * 64;
        f32x4 sfr[4];
        #pragma unroll
        for (int ks = 0; ks < 4; ++ks) {
            short8 kf = *(const short8*)(qk + (size_t)(b * LQm + k0 + ks * 16 + lr) * 512 + 256 + h * 32 + lg * 8);
            sfr[ks] = __builtin_amdgcn_mfma_f32_16x16x32_bf16(qf, kf, zero, 0, 0, 0);
        }
        float sv[4][4];
        #pragma unroll
        for (int ks = 0; ks < 4; ++ks) {
            bool valid = (k0 + ks * 16 + lr) < LQm;
            #pragma unroll
            for (int j = 0; j < 4; ++j)
                sv[ks][j] = valid ? sfr[ks][j] * scale : -1e30f;
        }
        float tm[4], newm[4], rr[4], ps[4];
        #pragma unroll
        for (int j = 0; j < 4; ++j)
            tm[j] = fmaxf(fmaxf(sv[0][j], sv[1][j]), fmaxf(sv[2][j], sv[3][j]));
        #pragma unroll
        for (int msk = 1; msk <= 8; msk <<= 1) {
            #pragma unroll
            for (int j = 0; j < 4; ++j) tm[j] = fmaxf(tm[j], __shfl_xor(tm[j], msk));
        }
        #pragma unroll
        for (int j = 0; j < 4; ++j) {
            newm[j] = fmaxf(mrow[j], tm[j]);
            rr[j] = __expf(mrow[j] - newm[j]);
            mrow[j] = newm[j];
            ps[j] = 0.f;
        }
        float pv[4][4];
        #pragma unroll
        for (int ks = 0; ks < 4; ++ks)
            #pragma unroll
            for (int j = 0; j < 4; ++j) {
                pv[ks][j] = __expf(sv[ks][j] - newm[j]);
                ps[j] += pv[ks][j];
            }
        #pragma unroll
        for (int msk = 1; msk <= 8; msk <<= 1) {
            #pragma unroll
            for (int j = 0; j < 4; ++j) ps[j] += __shfl_xor(ps[j], msk);
        }
        #pragma unroll
        for (int j = 0; j < 4; ++j) lrow[j] = lrow[j] * rr[j] + ps[j];
        #pragma unroll
        for (int n = 0; n < 2; ++n)
            #pragma unroll
            for (int j = 0; j < 4; ++j) accO[n][j] *= rr[j];
        #pragma unroll
        for (int ks = 0; ks < 4; ++ks)
            #pragma unroll
            for (int j = 0; j < 4; ++j)
                P_lds[w][lg * 4 + j][ks * 16 + lr] = f2bf(pv[ks][j]);
        #pragma unroll
        for (int kh2 = 0; kh2 < 2; ++kh2) {
            short8 pf = *(const short8*)(&P_lds[w][lr][kh2 * 32 + lg * 8]);
            #pragma unroll
            for (int n = 0; n < 2; ++n) {
                short8 vf = *(const short8*)(vtb + (size_t)(n * 16 + lr) * LQP + k0 + kh2 * 32 + lg * 8);
                accO[n] = __builtin_amdgcn_mfma_f32_16x16x32_bf16(pf, vf, accO[n], 0, 0, 0);
            }
        }
    }
    float inv[4];
    #pragma unroll
    for (int j = 0; j < 4; ++j) inv[j] = 1.0f / lrow[j];
    #pragma unroll
    for (int n = 0; n < 2; ++n)
        #pragma unroll
        for (int j = 0; j < 4; ++j) {
            int q = qt * 64 + w * 16 + lg * 4 + j;
            if (q < LQm)
                out[(size_t)(b * LQm + q) * 256 + h * 32 + n * 16 + lr] = f2bf(accO[n][j] * inv[j]);
        }
}

// -------------------- fused residual add + LayerNorm (wave per row) ---------
template <int DUAL, int QP>
__global__ __launch_bounds__(256) void add_ln_kernel(const float* __restrict__ x,
                                                     const float* __restrict__ r,
                                                     const float* __restrict__ w,
                                                     const float* __restrict__ b,
                                                     const float* __restrict__ qpos,
                                                     float* __restrict__ out,
                                                     unsigned short* __restrict__ outb,
                                                     unsigned short* __restrict__ outq) {
    int row = blockIdx.x * 4 + (threadIdx.x >> 6);
    int lane = threadIdx.x & 63;
    size_t i4 = (size_t)row * 64 + lane;
    float4 xv = reinterpret_cast<const float4*>(x)[i4];
    float4 rv = reinterpret_cast<const float4*>(r)[i4];
    float4 v = make_float4(xv.x + rv.x, xv.y + rv.y, xv.z + rv.z, xv.w + rv.w);
    float s = v.x + v.y + v.z + v.w;
    #pragma unroll
    for (int msk = 1; msk <= 32; msk <<= 1) s += __shfl_xor(s, msk);
    float mean = s * (1.0f / Dm);
    float4 dv = make_float4(v.x - mean, v.y - mean, v.z - mean, v.w - mean);
    float sq = dv.x * dv.x + dv.y * dv.y + dv.z * dv.z + dv.w * dv.w;
    #pragma unroll
    for (int msk = 1; msk <= 32; msk <<= 1) sq += __shfl_xor(sq, msk);
    float is = rsqrtf(sq * (1.0f / Dm) + 1e-5f);
    float4 wv = reinterpret_cast<const float4*>(w)[lane];
    float4 bv = reinterpret_cast<const float4*>(b)[lane];
    float4 res = make_float4(dv.x * is * wv.x + bv.x, dv.y * is * wv.y + bv.y,
                             dv.z * is * wv.z + bv.z, dv.w * is * wv.w + bv.w);
    reinterpret_cast<float4*>(out)[i4] = res;
    if (DUAL) {
        ushort4 u;
        u.x = f2bf(res.x); u.y = f2bf(res.y); u.z = f2bf(res.z); u.w = f2bf(res.w);
        reinterpret_cast<ushort4*>(outb)[i4] = u;
    }
    if (QP) {
        float4 qv = reinterpret_cast<const float4*>(qpos)[i4];
        ushort4 u;
        u.x = f2bf(res.x + qv.x); u.y = f2bf(res.y + qv.y);
        u.z = f2bf(res.z + qv.z); u.w = f2bf(res.w + qv.w);
        reinterpret_cast<ushort4*>(outq)[i4] = u;
    }
}

// -------------------- ms-deformable sampling: wave per query ----------------
__global__ __launch_bounds__(256) void msdeform_kernel(const unsigned short* __restrict__ value,
                                                       const float* __restrict__ ref,
                                                       const float* __restrict__ off,
                                                       const float* __restrict__ awl,
                                                       unsigned short* __restrict__ out) {
    const int HL[4] = {100, 50, 25, 13};
    const int ST[4] = {0, 10000, 12500, 13125};
    __shared__ float lsx[4][128], lsy[4][128], wtab[4][128];
    __shared__ float2 ctab[4][512];
    int wv = threadIdx.x >> 6, lane = threadIdx.x & 63;
    int m = blockIdx.x * 4 + wv;
    int b = m / LQm;

    #pragma unroll
    for (int e = lane; e < 128; e += 64) {
        int lev = (e >> 2) & 3;
        float rx = ref[((size_t)m * NLEVm + lev) * 2 + 0];
        float ry = ref[((size_t)m * NLEVm + lev) * 2 + 1];
        float ox = off[(size_t)m * 256 + e * 2 + 0];
        float oy = off[(size_t)m * 256 + e * 2 + 1];
        float Wf = (float)HL[lev];
        lsx[wv][e] = (rx + ox / Wf) * Wf - 0.5f;
        lsy[wv][e] = (ry + oy / Wf) * Wf - 0.5f;
        wtab[wv][e] = awl[(size_t)m * 128 + e];
    }
    __syncthreads();
    if (lane < NHm) {
        int h = lane;
        float mx = -1e30f;
        #pragma unroll
        for (int i = 0; i < 16; i++) mx = fmaxf(mx, wtab[wv][h * 16 + i]);
        float s = 0.f;
        #pragma unroll
        for (int i = 0; i < 16; i++) {
            float e = __expf(wtab[wv][h * 16 + i] - mx);
            wtab[wv][h * 16 + i] = e; s += e;
        }
        float inv = 1.0f / s;
        #pragma unroll
        for (int i = 0; i < 16; i++) wtab[wv][h * 16 + i] *= inv;
    }
    __syncthreads();
    #pragma unroll
    for (int j = 0; j < 8; ++j) {
        int e2 = lane * 8 + j;
        int c = e2 & 3, e = e2 >> 2;
        int lev = (e >> 2) & 3;
        int Wl = HL[lev];
        float lx = lsx[wv][e], ly = lsy[wv][e];
        float x0f = floorf(lx), y0f = floorf(ly);
        float fx = lx - x0f, fy = ly - y0f;
        int dx = c & 1, dy = c >> 1;
        int xi = (int)x0f + dx, yi = (int)y0f + dy;
        bool valid = (xi >= 0) && (xi < Wl) && (yi >= 0) && (yi < Wl);
        float wc = valid ? ((dx ? fx : 1.0f - fx) * (dy ? fy : 1.0f - fy)) * wtab[wv][e] : 0.f;
        int xc = min(max(xi, 0), Wl - 1), yc = min(max(yi, 0), Wl - 1);
        int row = b * LENm + ST[lev] + yc * Wl + xc;
        ctab[wv][e2] = make_float2(__int_as_float(row), wc);
    }
    __syncthreads();
    int h = lane >> 3, dg = lane & 7;
    const unsigned short* basep = value + h * 32 + dg * 4;
    float a0 = 0.f, a1 = 0.f, a2 = 0.f, a3 = 0.f;
    #pragma unroll
    for (int i = 0; i < 16; ++i) {
        #pragma unroll
        for (int c = 0; c < 4; ++c) {
            float2 cc = ctab[wv][(h * 16 + i) * 4 + c];
            int row = __float_as_int(cc.x);
            float wc = cc.y;
            ushort4 v = *reinterpret_cast<const ushort4*>(basep + (size_t)row * 256);
            a0 += wc * bf2f(v.x); a1 += wc * bf2f(v.y);
            a2 += wc * bf2f(v.z); a3 += wc * bf2f(v.w);
        }
    }
    ushort4 o;
    o.x = f2bf(a0); o.y = f2bf(a1); o.z = f2bf(a2); o.w = f2bf(a3);
    *reinterpret_cast<ushort4*>(out + (size_t)m * 256 + h * 32 + dg * 4) = o;
}

// ------------------------------------------------------------------
extern "C" void kernel_launch(void* const* d_in, const int* in_sizes, int n_in,
                              void* d_out, int out_size, void* d_ws, size_t ws_size,
                              hipStream_t stream) {
    const float* tgt   = (const float*)d_in[0];
    const float* qpos  = (const float*)d_in[1];
    const float* refp  = (const float*)d_in[2];
    const float* src   = (const float*)d_in[3];
    const float* qkv_w = (const float*)d_in[6];
    const float* qkv_b = (const float*)d_in[7];
    const float* out_w = (const float*)d_in[8];
    const float* out_b = (const float*)d_in[9];
    const float* ln2_w = (const float*)d_in[10];
    const float* ln2_b = (const float*)d_in[11];
    const float* val_w = (const float*)d_in[12];
    const float* val_b = (const float*)d_in[13];
    const float* off_w = (const float*)d_in[14];
    const float* off_b = (const float*)d_in[15];
    const float* aw_w  = (const float*)d_in[16];
    const float* aw_b  = (const float*)d_in[17];
    const float* op_w  = (const float*)d_in[18];
    const float* op_b  = (const float*)d_in[19];
    const float* ln1_w = (const float*)d_in[20];
    const float* ln1_b = (const float*)d_in[21];
    const float* w1    = (const float*)d_in[22];
    const float* b1    = (const float*)d_in[23];
    const float* w2    = (const float*)d_in[24];
    const float* b2    = (const float*)d_in[25];
    const float* ln3_w = (const float*)d_in[26];
    const float* ln3_b = (const float*)d_in[27];

    char* base = (char*)d_ws;
    unsigned short* value_bf  = (unsigned short*)(base);                      // 54,460,416
    unsigned short* hidden_bf = (unsigned short*)(base + 54460416);           // MQP*1024*2
    unsigned short* t2_bf     = (unsigned short*)(base + 54460416 + 14942208);
    unsigned short* qk_bf = (unsigned short*)(base + 108920832);              // MQP*512*2
    float* offb = (float*)(base + 108920832);                                 // aliases qk_bf (after flash)
    float* awb  = (float*)(base + 108920832 + 7372800);
    unsigned short* Vt = (unsigned short*)(base + 123666432);                 // 8*256*960*2
    float* S1   = (float*)(base + 123666432);                                 // aliases Vt (after flash)
    float* t1   = (float*)(base + 131039232);
    float* t2   = (float*)(base + 138412032);
    unsigned short* Qbf     = (unsigned short*)(base + 145784832);
    unsigned short* tgt_bf  = (unsigned short*)(base + 149520384);
    unsigned short* attn_bf = (unsigned short*)(base + 153255936);
    unsigned short* ca_bf   = (unsigned short*)(base + 156991488);
    unsigned short* BT_qkv  = (unsigned short*)(base + 160727040);            // [768][256]
    unsigned short* BT_out  = BT_qkv + 768 * 256;
    unsigned short* BT_val  = BT_out + 256 * 256;
    unsigned short* BT_off  = BT_val + 256 * 256;
    unsigned short* BT_aw   = BT_off + 256 * 256;                             // contiguous after BT_off
    unsigned short* BT_op   = BT_aw + 128 * 256;
    unsigned short* BT_w1   = BT_op + 256 * 256;
    unsigned short* BT_w2   = BT_w1 + 1024 * 256;
    float* outp = (float*)d_out;

    dim3 blk(256);
    wt_tiled<<<dim3(12, 4), blk, 0, stream>>>(qkv_w, BT_qkv, 768, 256);
    wt_tiled<<<dim3(4, 4),  blk, 0, stream>>>(out_w, BT_out, 256, 256);
    wt_tiled<<<dim3(4, 4),  blk, 0, stream>>>(val_w, BT_val, 256, 256);
    wt_tiled<<<dim3(4, 4),  blk, 0, stream>>>(off_w, BT_off, 256, 256);
    wt_tiled<<<dim3(2, 4),  blk, 0, stream>>>(aw_w,  BT_aw,  128, 256);
    wt_tiled<<<dim3(4, 4),  blk, 0, stream>>>(op_w,  BT_op,  256, 256);
    wt_tiled<<<dim3(16, 4), blk, 0, stream>>>(w1,    BT_w1, 1024, 256);
    wt_tiled<<<dim3(4, 16), blk, 0, stream>>>(w2,    BT_w2,  256, 1024);

    prep0<<<dim3(1824), blk, 0, stream>>>(tgt, qpos, tgt_bf, Qbf, MQ * Dm / 4, MQP * Dm / 4);

    // qkh (bf16) -> qk_bf
    bgemm<0, 1><<<dim3(57, 4), blk, 0, stream>>>(MQ, 512, 256, Qbf, BT_qkv, qkv_b, nullptr, nullptr, nullptr, qk_bf, 512);
    // Vt (bf16, transposed)
    bgemm<0, 2><<<dim3(57, 2), blk, 0, stream>>>(MQ, 256, 256, tgt_bf, BT_qkv + 512 * 256, qkv_b + 512, nullptr, nullptr, nullptr, Vt, 256);
    vtpad_kernel<<<dim3(480), blk, 0, stream>>>(Vt);
    flash_mfma<<<dim3(15, NHm, Bm), blk, 0, stream>>>(qk_bf, Vt, attn_bf);
    // sa proj -> S1
    bgemm<0, 0><<<dim3(57, 2), blk, 0, stream>>>(MQ, 256, 256, attn_bf, BT_out, out_b, nullptr, S1, nullptr, nullptr, 256);
    add_ln_kernel<0, 1><<<dim3(1800), blk, 0, stream>>>(tgt, S1, ln2_w, ln2_b, qpos, t1, nullptr, Qbf);
    // value = src @ val_w + val_b
    bgemm_vf<<<dim3(831, 2), blk, 0, stream>>>(MV, 256, 256, src, BT_val, val_b, value_bf, 256);
    // fused off (N=256) + aw (N=128) projection: N=384, BT_off||BT_aw contiguous
    bgemm<0, 3><<<dim3(57, 3), blk, 0, stream>>>(MQ, 384, 256, Qbf, BT_off, off_b, aw_b, offb, awb, nullptr, 0);
    msdeform_kernel<<<dim3(1800), blk, 0, stream>>>(value_bf, refp, offb, awb, ca_bf);
    // op proj -> S1
    bgemm<0, 0><<<dim3(57, 2), blk, 0, stream>>>(MQ, 256, 256, ca_bf, BT_op, op_b, nullptr, S1, nullptr, nullptr, 256);
    add_ln_kernel<1, 0><<<dim3(1800), blk, 0, stream>>>(t1, S1, ln1_w, ln1_b, nullptr, t2, t2_bf, nullptr);
    // ffn hidden
    bgemm<1, 1><<<dim3(57, 8), blk, 0, stream>>>(MQ, DFFNm, 256, t2_bf, BT_w1, b1, nullptr, nullptr, nullptr, hidden_bf, DFFNm);
    // ff
    bgemm<0, 0><<<dim3(57, 2), blk, 0, stream>>>(MQ, 256, 1024, hidden_bf, BT_w2, b2, nullptr, S1, nullptr, nullptr, 256);
    add_ln_kernel<0, 0><<<dim3(1800), blk, 0, stream>>>(t2, S1, ln3_w, ln3_b, nullptr, outp, nullptr, nullptr);
}